// Round 5
// baseline (177.545 us; speedup 1.0000x reference)
//
#include <hip/hip_runtime.h>
#include <hip/hip_bf16.h>
#include <math.h>

// Problem constants
#define BB   2
#define CC   256
#define NT   2304      // H*W
#define NTOK 4608      // B*NT
#define MM   16
#define NHD  4
#define HD   64
#define NBH  8
#define PARTS 4
#define LOG2E 1.4426950408889634f

typedef unsigned short u16;
typedef __attribute__((ext_vector_type(8))) short short8;
typedef __attribute__((ext_vector_type(4))) float f32x4;
typedef __attribute__((ext_vector_type(16))) float f32x16;

__device__ __forceinline__ float bf2f(u16 u) {
  return __uint_as_float(((unsigned)u) << 16);
}
__device__ __forceinline__ u16 f2bf(float f) {
  unsigned u = __float_as_uint(f);
  unsigned r = 0x7FFFu + ((u >> 16) & 1u);
  return (u16)((u + r) >> 16);
}
__device__ __forceinline__ float ld_any(const void* p, size_t i, int fp32) {
  return fp32 ? ((const float*)p)[i] : bf2f(((const u16*)p)[i]);
}

// per-block dtype detect (bf16 pairs read as u32: low 16 bits look like bf16)
__device__ __forceinline__ int detect_fp32_block(const unsigned* __restrict__ x) {
  __shared__ int cnt4[4];
  __shared__ int resf;
  int t = threadIdx.x;
  unsigned u = x[t];
  unsigned lo = u & 0xFFFFu;
  unsigned e = (lo >> 7) & 0xFFu;
  bool plausible = (lo == 0u) || (e >= 0x60u && e <= 0x88u);
  unsigned long long m = __ballot(plausible);
  if ((t & 63) == 0) cnt4[t >> 6] = __popcll(m);
  __syncthreads();
  if (t == 0) resf = ((cnt4[0] + cnt4[1] + cnt4[2] + cnt4[3]) < 128) ? 1 : 0;
  __syncthreads();
  return resf;
}

// ---------------- workspace layout (float offsets); flag = int at ws[0] ----
static constexpr size_t OFF_CB2   = 16;
static constexpr size_t OFF_CBQ   = OFF_CB2 + 256;
static constexpr size_t OFF_CBK   = OFF_CBQ + 256;
static constexpr size_t OFF_CBV   = OFF_CBK + 256;
static constexpr size_t OFF_CBO   = OFF_CBV + 256;
static constexpr size_t OFF_CLA   = OFF_CBO + 256;
static constexpr size_t OFF_CBETA = OFF_CLA + 16;
static constexpr size_t OFF_WQF   = 1344;                 // bf16 [32][256][8]
static constexpr size_t OFF_WKF   = OFF_WQF + 32768;
static constexpr size_t OFF_WVF   = OFF_WKF + 32768;
static constexpr size_t OFF_WOF   = OFF_WVF + 32768;
static constexpr size_t OFF_W2F   = OFF_WOF + 32768;      // bf16 [16][256][8]
static constexpr size_t OFF_QAUG  = OFF_W2F + 16384;      // bf16 [8][16][2304][8]
static constexpr size_t OFF_KAUG  = OFF_QAUG + 1179648;
static constexpr size_t OFF_V3    = OFF_KAUG + 1179648;   // bf16 [8][288][64][8] (row-permuted)
static constexpr size_t OFF_OPART = OFF_V3 + 589824;      // bf16 [4][8][2304][64]
static constexpr size_t OFF_LPART = OFF_OPART + 2359296;  // f32 [4][8][2304]
// end = OFF_LPART + 73728 = 5,530,944 floats ~ 22.1 MiB

// ================= K1: pack weights + convert smalls + flag ================
__global__ __launch_bounds__(256) void setup_kernel(
    const void* __restrict__ x_raw,
    const void* __restrict__ Wq_r, const void* __restrict__ Wk_r,
    const void* __restrict__ Wv_r, const void* __restrict__ Wo_r,
    const void* __restrict__ W2_r,
    const void* __restrict__ b2_r, const void* __restrict__ bq_r,
    const void* __restrict__ bk_r, const void* __restrict__ bv_r,
    const void* __restrict__ bo_r, const void* __restrict__ la_r,
    const void* __restrict__ beta_r,
    float* __restrict__ ws, short* __restrict__ ws16, int* __restrict__ flagp) {
  const int fp32 = detect_fp32_block((const unsigned*)x_raw);
  const int bid = blockIdx.x, t = threadIdx.x;
  if (bid == 0 && t == 0) *flagp = fp32;
  if (bid < 1152) {
    // pack weights to bf16 fragment layout: W[n][k] -> [k>>3][n][k&7]
    int idx = bid * 256 + t;   // < 294912
    const void* srcs[5] = {Wq_r, Wk_r, Wv_r, Wo_r, W2_r};
    const int elems[5] = {65536, 65536, 65536, 65536, 32768};
    const int ksh[5] = {8, 8, 8, 8, 7};
    const size_t dsts[5] = {OFF_WQF * 2, OFF_WKF * 2, OFF_WVF * 2, OFF_WOF * 2, OFF_W2F * 2};
    int m = 0, off = idx;
    while (off >= elems[m]) { off -= elems[m]; ++m; }
    int ks = ksh[m];
    int n = off >> ks, k = off & ((1 << ks) - 1);
    float v = ld_any(srcs[m], off, fp32);
    ws16[dsts[m] + ((size_t)(k >> 3) * 256 + n) * 8 + (k & 7)] = (short)f2bf(v);
  } else {
    int idx = (bid - 1152) * 256 + t;   // < 1285
    const void* srcs[7] = {b2_r, bq_r, bk_r, bv_r, bo_r, la_r, beta_r};
    const int sizes[7] = {256, 256, 256, 256, 256, 1, 4};
    const int dsts[7] = {(int)OFF_CB2, (int)OFF_CBQ, (int)OFF_CBK, (int)OFF_CBV,
                         (int)OFF_CBO, (int)OFF_CLA, (int)OFF_CBETA};
    if (idx < 1285) {
      int seg = 0, off = idx;
      while (off >= sizes[seg]) { off -= sizes[seg]; ++seg; }
      ws[(size_t)dsts[seg] + off] = ld_any(srcs[seg], off, fp32);
    }
  }
}

// ================= K2: fused MLP + prep-GEMM + QKV + aug (64 tokens/block) =
__global__ __launch_bounds__(256) void fused_prep(
    const void* __restrict__ x_raw, const void* __restrict__ phi_raw,
    const void* __restrict__ W1_r, const void* __restrict__ b1_r,
    const int* __restrict__ flagp,
    const short* __restrict__ wqf, const short* __restrict__ wkf,
    const short* __restrict__ wvf, const short* __restrict__ w2f,
    const float* __restrict__ bq, const float* __restrict__ bk,
    const float* __restrict__ bv, const float* __restrict__ b2,
    const float* __restrict__ la, const float* __restrict__ beta,
    short* __restrict__ Qaug, short* __restrict__ Kaug, short* __restrict__ V3) {
  __shared__ float phis[16][66];
  __shared__ float phisq_s[64];
  __shared__ float w1s[2048];
  __shared__ float b1s[128];
  __shared__ short hid[16][66][8];   // A-frags K=128: [kc][tok][8]
  __shared__ short xfs[32][66][8];   // A-frags K=256: [kc][tok][8]

  const int fp32 = *flagp;
  const int t = threadIdx.x;
  const int n0 = blockIdx.x * 64;
  const int b = (n0 >= NT) ? 1 : 0;
  const int nb0 = n0 - b * NT;

  // ---- load phi^T, W1, b1 into LDS
  #pragma unroll
  for (int i = 0; i < 4; ++i) {
    int idx = i * 256 + t;
    int m = idx >> 6, j = idx & 63;
    phis[m][j] = ld_any(phi_raw, ((size_t)(b * 16 + m)) * NT + nb0 + j, fp32);
  }
  #pragma unroll
  for (int i = 0; i < 8; ++i) w1s[i * 256 + t] = ld_any(W1_r, i * 256 + t, fp32);
  if (t < 128) b1s[t] = ld_any(b1_r, t, fp32);
  __syncthreads();

  // ---- phisq + GELU hidden -> hid frags
  if (t < 64) {
    float s = 0.f;
    #pragma unroll
    for (int m = 0; m < 16; ++m) { float p = phis[m][t]; s += p * p; }
    phisq_s[t] = s;
  }
  {
    const int tok = t & 63, qtr = t >> 6;
    float pr[16];
    #pragma unroll
    for (int m = 0; m < 16; ++m) pr[m] = phis[m][tok];
    #pragma unroll
    for (int cc = 0; cc < 4; ++cc) {
      union { u16 a[8]; short8 v; } pk;
      #pragma unroll
      for (int s8 = 0; s8 < 8; ++s8) {
        int c = qtr * 32 + cc * 8 + s8;
        float acc = b1s[c];
        #pragma unroll
        for (int m = 0; m < 16; ++m) acc += pr[m] * w1s[c * 16 + m];
        float g = 0.5f * acc * (1.f + erff(acc * 0.70710678118654752f));
        pk.a[s8] = f2bf(g);
      }
      *(short8*)&hid[qtr * 4 + cc][tok][0] = pk.v;
    }
  }
  __syncthreads();

  const int lane = t & 63, w = t >> 6;
  const int c32 = lane & 31, H = lane >> 5;
  const int tt = w & 1, chgrp = w >> 1;

  // ---- stage B: xf = hid @ W2^T + b2 + x^T  -> xfs frags
  #pragma unroll
  for (int j = 0; j < 4; ++j) {
    const int ch0 = (chgrp * 4 + j) * 32;
    f32x16 acc;
    #pragma unroll
    for (int r = 0; r < 16; ++r) acc[r] = 0.f;
    #pragma unroll
    for (int s = 0; s < 8; ++s) {
      short8 a = *(const short8*)&hid[2 * s + H][tt * 32 + c32][0];
      short8 bb = *(const short8*)&w2f[((size_t)(2 * s + H) * 256 + ch0 + c32) * 8];
      acc = __builtin_amdgcn_mfma_f32_32x32x16_bf16(a, bb, acc, 0, 0, 0);
    }
    const int ch = ch0 + c32;
    const float bias = b2[ch];
    #pragma unroll
    for (int g = 0; g < 4; ++g) {
      int tok0 = tt * 32 + 8 * g + 4 * H;
      size_t xoff = ((size_t)(b * CC + ch)) * NT + nb0 + tok0;
      float4 xv;
      if (fp32) {
        xv = *(const float4*)&((const float*)x_raw)[xoff];
      } else {
        ushort4 xu = *(const ushort4*)&((const u16*)x_raw)[xoff];
        xv = make_float4(bf2f(xu.x), bf2f(xu.y), bf2f(xu.z), bf2f(xu.w));
      }
      float vals[4] = {xv.x, xv.y, xv.z, xv.w};
      #pragma unroll
      for (int e = 0; e < 4; ++e) {
        float v = acc[4 * g + e] + bias + vals[e];
        xfs[ch >> 3][tok0 + e][ch & 7] = (short)f2bf(v);
      }
    }
  }
  __syncthreads();

  // ---- stage C: Q/K/V projections from xfs (K=256)
  #pragma unroll
  for (int z = 0; z < 3; ++z) {
    const short* wf = (z == 0) ? wqf : (z == 1) ? wkf : wvf;
    const float* bias = (z == 0) ? bq : (z == 1) ? bk : bv;
    const float sc = (z == 0) ? 0.125f * LOG2E : 1.f;   // fold softmax scale+log2e into Q
    #pragma unroll
    for (int j = 0; j < 4; ++j) {
      const int ch0 = (chgrp * 4 + j) * 32;
      f32x16 acc;
      #pragma unroll
      for (int r = 0; r < 16; ++r) acc[r] = 0.f;
      #pragma unroll
      for (int s = 0; s < 16; ++s) {
        short8 a = *(const short8*)&xfs[2 * s + H][tt * 32 + c32][0];
        short8 bb = *(const short8*)&wf[((size_t)(2 * s + H) * 256 + ch0 + c32) * 8];
        acc = __builtin_amdgcn_mfma_f32_32x32x16_bf16(a, bb, acc, 0, 0, 0);
      }
      const int ch = ch0 + c32;
      const int h = ch >> 6, chh = ch & 63;
      const int bh = b * NHD + h;
      const float bv_ = bias[ch];
      if (z < 2) {
        short* dst = (z == 0) ? Qaug : Kaug;
        const int kq = chh >> 3, sub = chh & 7;
        #pragma unroll
        for (int r = 0; r < 16; ++r) {
          int tok = tt * 32 + (r & 3) + 8 * (r >> 2) + 4 * H;
          int nloc = nb0 + tok;
          dst[((size_t)(bh * 16 + kq) * NT + nloc) * 8 + sub] =
              (short)f2bf((acc[r] + bv_) * sc);
        }
      } else {
        const int d = chh;
        #pragma unroll
        for (int r = 0; r < 16; ++r) {
          int tok = tt * 32 + (r & 3) + 8 * (r >> 2) + 4 * H;
          int n = nb0 + tok;
          // row-permuted V3 so P's natural register order is the A-operand order
          int chunk = (n >> 6) * 8 + ((n >> 5) & 1) * 4 + ((n >> 4) & 1) * 2 + ((n >> 2) & 1);
          int jj = (n & 3) + 4 * ((n >> 3) & 1);
          V3[((size_t)(bh * 288 + chunk) * 64 + d) * 8 + jj] = (short)f2bf(acc[r] + bv_);
        }
      }
    }
  }

  // ---- aug: Q/K chunks 8..15 (geodesic terms, log2e folded)
  {
    const int tok = t & 63, h = t >> 6;
    const int bh = b * NHD + h;
    const int n = nb0 + tok;
    float coef = -__expf(la[0]) * beta[h] * 0.17677669529663687f * LOG2E;
    float s2c = -2.f * coef;
    u16 sflip = (s2c < 0.f) ? 0x8000u : 0u;
    float s = sqrtf(fabsf(s2c));
    u16 qh[16], ql[16];
    #pragma unroll
    for (int m = 0; m < MM; ++m) {
      float v = s * phis[m][tok];
      u16 hv = f2bf(v);
      qh[m] = hv;
      ql[m] = f2bf(v - bf2f(hv));
    }
    float cp = coef * phisq_s[tok];
    u16 chi = f2bf(cp);
    u16 clo = f2bf(cp - bf2f(chi));
    union { u16 a[8]; short8 v; } ch;
    auto wr = [&](short* dst, int kq) {
      *(short8*)&dst[((size_t)(bh * 16 + kq) * NT + n) * 8] = ch.v;
    };
    #pragma unroll
    for (int p = 0; p < 8; ++p) ch.a[p] = qh[p];      wr(Qaug, 8);
    #pragma unroll
    for (int p = 0; p < 8; ++p) ch.a[p] = qh[8 + p];  wr(Qaug, 9);
    #pragma unroll
    for (int p = 0; p < 8; ++p) ch.a[p] = ql[p];      wr(Qaug, 10);
    #pragma unroll
    for (int p = 0; p < 8; ++p) ch.a[p] = ql[8 + p];  wr(Qaug, 11);
    #pragma unroll
    for (int p = 0; p < 8; ++p) ch.a[p] = qh[p];      wr(Qaug, 12);
    #pragma unroll
    for (int p = 0; p < 8; ++p) ch.a[p] = qh[8 + p];  wr(Qaug, 13);
    #pragma unroll
    for (int p = 0; p < 8; ++p) ch.a[p] = 0;
    ch.a[0] = 0x3F80u; ch.a[1] = 0x3F80u;             wr(Qaug, 14);
    ch.a[0] = 0; ch.a[1] = 0;                         wr(Qaug, 15);
    #pragma unroll
    for (int p = 0; p < 8; ++p) ch.a[p] = qh[p] ? (u16)(qh[p] ^ sflip) : (u16)0;      wr(Kaug, 8);
    #pragma unroll
    for (int p = 0; p < 8; ++p) ch.a[p] = qh[8+p] ? (u16)(qh[8+p] ^ sflip) : (u16)0;  wr(Kaug, 9);
    #pragma unroll
    for (int p = 0; p < 8; ++p) ch.a[p] = qh[p] ? (u16)(qh[p] ^ sflip) : (u16)0;      wr(Kaug, 10);
    #pragma unroll
    for (int p = 0; p < 8; ++p) ch.a[p] = qh[8+p] ? (u16)(qh[8+p] ^ sflip) : (u16)0;  wr(Kaug, 11);
    #pragma unroll
    for (int p = 0; p < 8; ++p) ch.a[p] = ql[p] ? (u16)(ql[p] ^ sflip) : (u16)0;      wr(Kaug, 12);
    #pragma unroll
    for (int p = 0; p < 8; ++p) ch.a[p] = ql[8+p] ? (u16)(ql[8+p] ^ sflip) : (u16)0;  wr(Kaug, 13);
    #pragma unroll
    for (int p = 0; p < 8; ++p) ch.a[p] = 0;
    ch.a[0] = chi; ch.a[1] = clo;                     wr(Kaug, 14);
    ch.a[0] = 0; ch.a[1] = 0;                         wr(Kaug, 15);
  }
}

// ================= K3: attention, 32x32 MFMA, dbuf prefetch, no exchange ===
__global__ __launch_bounds__(256) void attn_v3(
    const short* __restrict__ Qaug, const short* __restrict__ Kaug,
    const short* __restrict__ V3,
    u16* __restrict__ opart, float* __restrict__ lpart) {
  __shared__ float omrg[2][2][16][64];   // 16 KB: kh-pair merge
  __shared__ float lmrg[64];
  const int t = threadIdx.x, lane = t & 63, w = t >> 6;
  const int qh = w >> 1, kh = w & 1;
  const int c32 = lane & 31, H = lane >> 5;
  const int qt = blockIdx.x, bh = blockIdx.y, part = blockIdx.z;
  const int q0 = qt * 64;
  const int qrow = q0 + qh * 32 + c32;

  const short* qbase = Qaug + (size_t)bh * 16 * NT * 8;
  const short* kbase = Kaug + (size_t)bh * 16 * NT * 8;
  const short* vbase = V3 + (size_t)bh * 288 * 64 * 8;

  short8 qf[8];
  #pragma unroll
  for (int s = 0; s < 8; ++s)
    qf[s] = *(const short8*)&qbase[((size_t)(2 * s + H) * NT + qrow) * 8];

  f32x16 o[2];
  #pragma unroll
  for (int nt = 0; nt < 2; ++nt)
    #pragma unroll
    for (int r = 0; r < 16; ++r) o[nt][r] = 0.f;
  float lsum = 0.f;

  const int kt0 = part * 9;
  short8 kf[2][8], vf[2][4];
  {
    int j = kt0 * 64 + kh * 32 + c32;
    #pragma unroll
    for (int s = 0; s < 8; ++s)
      kf[0][s] = *(const short8*)&kbase[((size_t)(2 * s + H) * NT + j) * 8];
    #pragma unroll
    for (int st = 0; st < 2; ++st)
      #pragma unroll
      for (int nt = 0; nt < 2; ++nt)
        vf[0][st * 2 + nt] = *(const short8*)&vbase[
            ((size_t)(kt0 * 8 + kh * 4 + st * 2 + H) * 64 + nt * 32 + c32) * 8];
  }

  #pragma unroll
  for (int it = 0; it < 9; ++it) {
    const int cur = it & 1, nxt = cur ^ 1;
    if (it < 8) {   // prefetch next tile at top of iteration (max lead time)
      int ktn = kt0 + it + 1;
      int jn = ktn * 64 + kh * 32 + c32;
      #pragma unroll
      for (int s = 0; s < 8; ++s)
        kf[nxt][s] = *(const short8*)&kbase[((size_t)(2 * s + H) * NT + jn) * 8];
      #pragma unroll
      for (int st = 0; st < 2; ++st)
        #pragma unroll
        for (int nt = 0; nt < 2; ++nt)
          vf[nxt][st * 2 + nt] = *(const short8*)&vbase[
              ((size_t)(ktn * 8 + kh * 4 + st * 2 + H) * 64 + nt * 32 + c32) * 8];
    }

    // S^T quadrant: D[j][i], lane col = i; two chains for MFMA ILP
    f32x16 s0, s1;
    #pragma unroll
    for (int r = 0; r < 16; ++r) { s0[r] = 0.f; s1[r] = 0.f; }
    #pragma unroll
    for (int s = 0; s < 4; ++s)
      s0 = __builtin_amdgcn_mfma_f32_32x32x16_bf16(kf[cur][s], qf[s], s0, 0, 0, 0);
    #pragma unroll
    for (int s = 4; s < 8; ++s)
      s1 = __builtin_amdgcn_mfma_f32_32x32x16_bf16(kf[cur][s], qf[s], s1, 0, 0, 0);

    float p[16];
    #pragma unroll
    for (int r = 0; r < 16; ++r) { p[r] = exp2f(s0[r] + s1[r]); lsum += p[r]; }

    // P A-frags: natural register order (V3 rows pre-permuted) — no exchange
    short8 pf[2];
    #pragma unroll
    for (int st = 0; st < 2; ++st) {
      union { unsigned u[4]; short8 v; } pk;
      #pragma unroll
      for (int j2 = 0; j2 < 4; ++j2) {
        __hip_bfloat162 hh = __float22bfloat162_rn(
            make_float2(p[8 * st + 2 * j2], p[8 * st + 2 * j2 + 1]));
        pk.u[j2] = *(unsigned*)&hh;
      }
      pf[st] = pk.v;
    }

    #pragma unroll
    for (int st = 0; st < 2; ++st)
      #pragma unroll
      for (int nt = 0; nt < 2; ++nt)
        o[nt] = __builtin_amdgcn_mfma_f32_32x32x16_bf16(pf[st], vf[cur][st * 2 + nt],
                                                        o[nt], 0, 0, 0);
  }

  lsum += __shfl_xor(lsum, 32, 64);

  // in-block kh-pair merge (fp32), then one bf16 partial per part
  if (kh == 1) {
    #pragma unroll
    for (int nt = 0; nt < 2; ++nt)
      #pragma unroll
      for (int r = 0; r < 16; ++r) omrg[qh][nt][r][lane] = o[nt][r];
    if (H == 0) lmrg[qh * 32 + c32] = lsum;
  }
  __syncthreads();
  if (kh == 0) {
    float lt = lsum + lmrg[qh * 32 + c32];
    u16* ob = opart + ((size_t)(part * NBH + bh)) * NT * 64;
    #pragma unroll
    for (int nt = 0; nt < 2; ++nt)
      #pragma unroll
      for (int r = 0; r < 16; ++r) {
        float v = o[nt][r] + omrg[qh][nt][r][lane];
        int row = q0 + qh * 32 + (r & 3) + 8 * (r >> 2) + 4 * H;
        ob[(size_t)row * 64 + nt * 32 + c32] = f2bf(v);
      }
    if (H == 0)
      lpart[((size_t)(part * NBH + bh)) * NT + q0 + qh * 32 + c32] = lt;
  }
}

// ================= K4: merge 4 partials + out-projection (64 tokens/block) =
__global__ __launch_bounds__(256) void merge_oproj(
    const u16* __restrict__ opart, const float* __restrict__ lpart,
    const short* __restrict__ wof, const float* __restrict__ bo,
    void* __restrict__ outp, const int* __restrict__ flagp) {
  __shared__ short afragB[32][66][8];   // B-frags: [kc=c>>3][tok][c&7]
  const int fp32 = *flagp;
  const int t = threadIdx.x;
  const int n0 = blockIdx.x * 64;
  const int b = (n0 >= NT) ? 1 : 0;
  const int nb0 = n0 - b * NT;

  // phase 1: merge partials -> normalized attention output frags in LDS
  #pragma unroll 4
  for (int i = 0; i < 64; ++i) {
    int idx = i * 256 + t;   // < 16384 = 4h * 64tok * 64d
    int d = idx & 63, tok = (idx >> 6) & 63, h = idx >> 12;
    int bh = b * NHD + h, n = nb0 + tok;
    float os = 0.f, ls = 0.f;
    #pragma unroll
    for (int p = 0; p < PARTS; ++p) {
      os += bf2f(opart[((size_t)(p * NBH + bh) * NT + n) * 64 + d]);
      ls += lpart[(size_t)(p * NBH + bh) * NT + n];
    }
    int c = h * 64 + d;
    afragB[c >> 3][tok][c & 7] = (short)f2bf(os / ls);
  }
  __syncthreads();

  // phase 2: out = attn @ Wo^T + bo, computed as D[ch][tok] -> coalesced store
  const int lane = t & 63, w = t >> 6;
  const int c32 = lane & 31, H = lane >> 5;
  const int tt = w & 1, chgrp = w >> 1;
  #pragma unroll
  for (int j = 0; j < 4; ++j) {
    const int ch0 = (chgrp * 4 + j) * 32;
    f32x16 acc;
    #pragma unroll
    for (int r = 0; r < 16; ++r) acc[r] = 0.f;
    #pragma unroll
    for (int s = 0; s < 16; ++s) {
      short8 a = *(const short8*)&wof[((size_t)(2 * s + H) * 256 + ch0 + c32) * 8];
      short8 bb = *(const short8*)&afragB[2 * s + H][tt * 32 + c32][0];
      acc = __builtin_amdgcn_mfma_f32_32x32x16_bf16(a, bb, acc, 0, 0, 0);
    }
    #pragma unroll
    for (int r = 0; r < 16; ++r) {
      int co = ch0 + (r & 3) + 8 * (r >> 2) + 4 * H;
      float v = acc[r] + bo[co];
      size_t off = ((size_t)(b * CC + co)) * NT + nb0 + tt * 32 + c32;
      if (fp32) ((float*)outp)[off] = v;
      else      ((u16*)outp)[off] = f2bf(v);
    }
  }
}

extern "C" void kernel_launch(void* const* d_in, const int* in_sizes, int n_in,
                              void* d_out, int out_size, void* d_ws, size_t ws_size,
                              hipStream_t stream) {
  float* ws = (float*)d_ws;
  short* ws16 = (short*)d_ws;
  int* flag = (int*)d_ws;

  float* cb2 = ws + OFF_CB2;
  float* cbq = ws + OFF_CBQ; float* cbk = ws + OFF_CBK; float* cbv = ws + OFF_CBV;
  float* cbo = ws + OFF_CBO; float* cla = ws + OFF_CLA; float* cbeta = ws + OFF_CBETA;
  short* wqf = ws16 + OFF_WQF * 2;
  short* wkf = ws16 + OFF_WKF * 2;
  short* wvf = ws16 + OFF_WVF * 2;
  short* wof = ws16 + OFF_WOF * 2;
  short* w2f = ws16 + OFF_W2F * 2;
  short* qaug = ws16 + OFF_QAUG * 2;
  short* kaug = ws16 + OFF_KAUG * 2;
  short* v3   = ws16 + OFF_V3 * 2;
  u16*   opart = (u16*)(ws16 + OFF_OPART * 2);
  float* lpart = ws + OFF_LPART;

  setup_kernel<<<1158, 256, 0, stream>>>(
      d_in[0], d_in[3], d_in[5], d_in[7], d_in[9], d_in[13],
      d_in[14], d_in[4], d_in[6], d_in[8], d_in[10], d_in[15], d_in[16],
      ws, ws16, flag);
  fused_prep<<<72, 256, 0, stream>>>(
      d_in[0], d_in[1], d_in[11], d_in[12], flag,
      wqf, wkf, wvf, w2f, cbq, cbk, cbv, cb2, cla, cbeta,
      qaug, kaug, v3);
  attn_v3<<<dim3(36, 8, PARTS), 256, 0, stream>>>(qaug, kaug, v3, opart, lpart);
  merge_oproj<<<72, 256, 0, stream>>>(opart, lpart, wof, cbo, d_out, flag);
}

// Round 6
// 157.775 us; speedup vs baseline: 1.1253x; 1.1253x over previous
//
#include <hip/hip_runtime.h>
#include <hip/hip_bf16.h>
#include <math.h>

// Problem constants
#define BB   2
#define CC   256
#define NT   2304      // H*W
#define NTOK 4608      // B*NT
#define MM   16
#define NHD  4
#define HD   64
#define NBH  8
#define LOG2E 1.4426950408889634f

typedef unsigned short u16;
typedef __attribute__((ext_vector_type(8))) short short8;
typedef __attribute__((ext_vector_type(4))) float f32x4;
typedef __attribute__((ext_vector_type(16))) float f32x16;

__device__ __forceinline__ float bf2f(u16 u) {
  return __uint_as_float(((unsigned)u) << 16);
}
__device__ __forceinline__ u16 f2bf(float f) {
  unsigned u = __float_as_uint(f);
  unsigned r = 0x7FFFu + ((u >> 16) & 1u);
  return (u16)((u + r) >> 16);
}
__device__ __forceinline__ float ld_any(const void* p, size_t i, int fp32) {
  return fp32 ? ((const float*)p)[i] : bf2f(((const u16*)p)[i]);
}

// per-block dtype detect (bf16 pairs read as u32: low 16 bits look like bf16)
__device__ __forceinline__ int detect_fp32_block(const unsigned* __restrict__ x) {
  __shared__ int cnt4[4];
  __shared__ int resf;
  int t = threadIdx.x;
  unsigned u = x[t & 255];
  unsigned lo = u & 0xFFFFu;
  unsigned e = (lo >> 7) & 0xFFu;
  bool plausible = (lo == 0u) || (e >= 0x60u && e <= 0x88u);
  unsigned long long m = __ballot(plausible);
  if ((t & 63) == 0 && (t >> 6) < 4) cnt4[t >> 6] = __popcll(m);
  __syncthreads();
  if (t == 0) resf = ((cnt4[0] + cnt4[1] + cnt4[2] + cnt4[3]) < 128) ? 1 : 0;
  __syncthreads();
  return resf;
}

// ---------------- workspace layout (float offsets); flag = int at ws[0] ----
static constexpr size_t OFF_CB2   = 16;
static constexpr size_t OFF_CBQ   = OFF_CB2 + 256;
static constexpr size_t OFF_CBK   = OFF_CBQ + 256;
static constexpr size_t OFF_CBV   = OFF_CBK + 256;
static constexpr size_t OFF_CBO   = OFF_CBV + 256;
static constexpr size_t OFF_CLA   = OFF_CBO + 256;
static constexpr size_t OFF_CBETA = OFF_CLA + 16;
static constexpr size_t OFF_WQF   = 1344;                 // bf16 [32][256][8]
static constexpr size_t OFF_WKF   = OFF_WQF + 32768;
static constexpr size_t OFF_WVF   = OFF_WKF + 32768;
static constexpr size_t OFF_WOF   = OFF_WVF + 32768;
static constexpr size_t OFF_W2F   = OFF_WOF + 32768;      // bf16 [16][256][8]
static constexpr size_t OFF_XFB   = OFF_W2F + 16384;      // bf16 [32][4608][8]
static constexpr size_t OFF_QAUG  = OFF_XFB + 589824;     // bf16 [8][16][2304][8]
static constexpr size_t OFF_KAUG  = OFF_QAUG + 1179648;
static constexpr size_t OFF_V3    = OFF_KAUG + 1179648;   // bf16 [8][288][64][8] (row-permuted)
static constexpr size_t OFF_PHIF  = OFF_V3 + 589824;      // f32 [4608][16]
static constexpr size_t OFF_PHISQ = OFF_PHIF + 73728;     // f32 [4608]
static constexpr size_t OFF_AFRAG = OFF_PHISQ + 4608;     // bf16 [32][4608][8]
// end ~ 4.36M floats ~ 17.4 MiB

// ================= K1: pack weights + convert smalls + flag ================
__global__ __launch_bounds__(256) void setup_kernel(
    const void* __restrict__ x_raw,
    const void* __restrict__ Wq_r, const void* __restrict__ Wk_r,
    const void* __restrict__ Wv_r, const void* __restrict__ Wo_r,
    const void* __restrict__ W2_r,
    const void* __restrict__ b2_r, const void* __restrict__ bq_r,
    const void* __restrict__ bk_r, const void* __restrict__ bv_r,
    const void* __restrict__ bo_r, const void* __restrict__ la_r,
    const void* __restrict__ beta_r,
    float* __restrict__ ws, short* __restrict__ ws16, int* __restrict__ flagp) {
  const int fp32 = detect_fp32_block((const unsigned*)x_raw);
  const int bid = blockIdx.x, t = threadIdx.x;
  if (bid == 0 && t == 0) *flagp = fp32;
  if (bid < 1152) {
    // pack weights to bf16 fragment layout: W[n][k] -> [k>>3][n][k&7]
    int idx = bid * 256 + t;   // < 294912
    const void* srcs[5] = {Wq_r, Wk_r, Wv_r, Wo_r, W2_r};
    const int elems[5] = {65536, 65536, 65536, 65536, 32768};
    const int ksh[5] = {8, 8, 8, 8, 7};
    const size_t dsts[5] = {OFF_WQF * 2, OFF_WKF * 2, OFF_WVF * 2, OFF_WOF * 2, OFF_W2F * 2};
    int m = 0, off = idx;
    while (off >= elems[m]) { off -= elems[m]; ++m; }
    int ks = ksh[m];
    int n = off >> ks, k = off & ((1 << ks) - 1);
    float v = ld_any(srcs[m], off, fp32);
    ws16[dsts[m] + ((size_t)(k >> 3) * 256 + n) * 8 + (k & 7)] = (short)f2bf(v);
  } else {
    int idx = (bid - 1152) * 256 + t;   // < 1285
    const void* srcs[7] = {b2_r, bq_r, bk_r, bv_r, bo_r, la_r, beta_r};
    const int sizes[7] = {256, 256, 256, 256, 256, 1, 4};
    const int dsts[7] = {(int)OFF_CB2, (int)OFF_CBQ, (int)OFF_CBK, (int)OFF_CBV,
                         (int)OFF_CBO, (int)OFF_CLA, (int)OFF_CBETA};
    if (idx < 1285) {
      int seg = 0, off = idx;
      while (off >= sizes[seg]) { off -= sizes[seg]; ++seg; }
      ws[(size_t)dsts[seg] + off] = ld_any(srcs[seg], off, fp32);
    }
  }
}

// ================= K2: MLP + xf GEMM, channel-split (72 tiles x 4 chgroups) =
__global__ __launch_bounds__(256) void prep_xf(
    const void* __restrict__ x_raw, const void* __restrict__ phi_raw,
    const void* __restrict__ W1_r, const void* __restrict__ b1_r,
    const int* __restrict__ flagp,
    const short* __restrict__ w2f, const float* __restrict__ b2,
    float* __restrict__ phif, float* __restrict__ phisq,
    short* __restrict__ xfb) {
  __shared__ float phis[16][66];
  __shared__ float phisq_s[64];
  __shared__ float w1s[2048];
  __shared__ float b1s[128];
  __shared__ short hid[16][66][8];   // A-frags K=128: [kc][tok][8]

  const int fp32 = *flagp;
  const int t = threadIdx.x;
  const int n0 = blockIdx.x * 64, cg = blockIdx.y;
  const int b = (n0 >= NT) ? 1 : 0;
  const int nb0 = n0 - b * NT;

  #pragma unroll
  for (int i = 0; i < 4; ++i) {
    int idx = i * 256 + t;
    int m = idx >> 6, j = idx & 63;
    phis[m][j] = ld_any(phi_raw, ((size_t)(b * 16 + m)) * NT + nb0 + j, fp32);
  }
  #pragma unroll
  for (int i = 0; i < 8; ++i) w1s[i * 256 + t] = ld_any(W1_r, i * 256 + t, fp32);
  if (t < 128) b1s[t] = ld_any(b1_r, t, fp32);
  __syncthreads();

  if (t < 64) {
    float s = 0.f;
    #pragma unroll
    for (int m = 0; m < 16; ++m) { float p = phis[m][t]; s += p * p; }
    phisq_s[t] = s;
    if (cg == 0) phisq[n0 + t] = s;
  }
  if (cg == 0) {
    #pragma unroll
    for (int i = 0; i < 4; ++i) {
      int idx = i * 256 + t;
      int j = idx >> 4, m = idx & 15;
      phif[(size_t)(n0 + j) * 16 + m] = phis[m][j];
    }
  }
  {
    const int tok = t & 63, qtr = t >> 6;
    float pr[16];
    #pragma unroll
    for (int m = 0; m < 16; ++m) pr[m] = phis[m][tok];
    #pragma unroll
    for (int cc = 0; cc < 4; ++cc) {
      union { u16 a[8]; short8 v; } pk;
      #pragma unroll
      for (int s8 = 0; s8 < 8; ++s8) {
        int c = qtr * 32 + cc * 8 + s8;
        float acc = b1s[c];
        #pragma unroll
        for (int m = 0; m < 16; ++m) acc += pr[m] * w1s[c * 16 + m];
        float g = 0.5f * acc * (1.f + erff(acc * 0.70710678118654752f));
        pk.a[s8] = f2bf(g);
      }
      *(short8*)&hid[qtr * 4 + cc][tok][0] = pk.v;
    }
  }
  __syncthreads();

  // xf = hid @ W2^T + b2 + x^T for this block's 64 channels
  const int lane = t & 63, w = t >> 6;
  const int c32 = lane & 31, H = lane >> 5;
  const int tt = w & 1, chh = w >> 1;
  const int ch0 = cg * 64 + chh * 32;
  f32x16 acc;
  #pragma unroll
  for (int r = 0; r < 16; ++r) acc[r] = 0.f;
  #pragma unroll
  for (int s = 0; s < 8; ++s) {
    short8 a = *(const short8*)&hid[2 * s + H][tt * 32 + c32][0];
    short8 bb = *(const short8*)&w2f[((size_t)(2 * s + H) * 256 + ch0 + c32) * 8];
    acc = __builtin_amdgcn_mfma_f32_32x32x16_bf16(a, bb, acc, 0, 0, 0);
  }
  const int ch = ch0 + c32;
  const float bias = b2[ch];
  #pragma unroll
  for (int g = 0; g < 4; ++g) {
    int tok0 = tt * 32 + 8 * g + 4 * H;
    size_t xoff = ((size_t)(b * CC + ch)) * NT + nb0 + tok0;
    float4 xv;
    if (fp32) {
      xv = *(const float4*)&((const float*)x_raw)[xoff];
    } else {
      ushort4 xu = *(const ushort4*)&((const u16*)x_raw)[xoff];
      xv = make_float4(bf2f(xu.x), bf2f(xu.y), bf2f(xu.z), bf2f(xu.w));
    }
    float vals[4] = {xv.x, xv.y, xv.z, xv.w};
    #pragma unroll
    for (int e = 0; e < 4; ++e) {
      float v = acc[4 * g + e] + bias + vals[e];
      int gtok = n0 + tok0 + e;
      xfb[((size_t)(ch >> 3) * NTOK + gtok) * 8 + (ch & 7)] = (short)f2bf(v);
    }
  }
}

// ================= K3: QKV projection (MFMA) + fused aug ===================
__global__ __launch_bounds__(256) void qkv_aug(
    const short* __restrict__ xfb,
    const short* __restrict__ wqf, const short* __restrict__ wkf,
    const short* __restrict__ wvf,
    const float* __restrict__ bq, const float* __restrict__ bk,
    const float* __restrict__ bv,
    const float* __restrict__ phif, const float* __restrict__ phisq,
    const float* __restrict__ la, const float* __restrict__ beta,
    short* __restrict__ Qaug, short* __restrict__ Kaug, short* __restrict__ V3) {
  const int z = blockIdx.z;
  if (z == 3) {
    // ---- aug: fill Qaug/Kaug chunks 8..15 (geodesic, log2e folded)
    if (blockIdx.y != 0) return;
    int idx = blockIdx.x * 256 + threadIdx.x;
    if (idx >= NBH * NT) return;
    int bh = idx / NT, n = idx - bh * NT;
    int b = bh >> 2, h = bh & 3;
    float coef = -__expf(la[0]) * beta[h] * 0.17677669529663687f * LOG2E;
    float s2c = -2.f * coef;
    u16 sflip = (s2c < 0.f) ? 0x8000u : 0u;
    float s = sqrtf(fabsf(s2c));
    u16 qh[16], ql[16];
    #pragma unroll
    for (int m = 0; m < MM; ++m) {
      float v = s * phif[(size_t)(b * NT + n) * MM + m];
      u16 hv = f2bf(v);
      qh[m] = hv;
      ql[m] = f2bf(v - bf2f(hv));
    }
    float cp = coef * phisq[b * NT + n];
    u16 chi = f2bf(cp);
    u16 clo = f2bf(cp - bf2f(chi));
    union { u16 a[8]; short8 v; } ch;
    auto wr = [&](short* dst, int kq) {
      *(short8*)&dst[((size_t)(bh * 16 + kq) * NT + n) * 8] = ch.v;
    };
    #pragma unroll
    for (int p = 0; p < 8; ++p) ch.a[p] = qh[p];      wr(Qaug, 8);
    #pragma unroll
    for (int p = 0; p < 8; ++p) ch.a[p] = qh[8 + p];  wr(Qaug, 9);
    #pragma unroll
    for (int p = 0; p < 8; ++p) ch.a[p] = ql[p];      wr(Qaug, 10);
    #pragma unroll
    for (int p = 0; p < 8; ++p) ch.a[p] = ql[8 + p];  wr(Qaug, 11);
    #pragma unroll
    for (int p = 0; p < 8; ++p) ch.a[p] = qh[p];      wr(Qaug, 12);
    #pragma unroll
    for (int p = 0; p < 8; ++p) ch.a[p] = qh[8 + p];  wr(Qaug, 13);
    #pragma unroll
    for (int p = 0; p < 8; ++p) ch.a[p] = 0;
    ch.a[0] = 0x3F80u; ch.a[1] = 0x3F80u;             wr(Qaug, 14);
    ch.a[0] = 0; ch.a[1] = 0;                         wr(Qaug, 15);
    #pragma unroll
    for (int p = 0; p < 8; ++p) ch.a[p] = qh[p] ? (u16)(qh[p] ^ sflip) : (u16)0;      wr(Kaug, 8);
    #pragma unroll
    for (int p = 0; p < 8; ++p) ch.a[p] = qh[8+p] ? (u16)(qh[8+p] ^ sflip) : (u16)0;  wr(Kaug, 9);
    #pragma unroll
    for (int p = 0; p < 8; ++p) ch.a[p] = qh[p] ? (u16)(qh[p] ^ sflip) : (u16)0;      wr(Kaug, 10);
    #pragma unroll
    for (int p = 0; p < 8; ++p) ch.a[p] = qh[8+p] ? (u16)(qh[8+p] ^ sflip) : (u16)0;  wr(Kaug, 11);
    #pragma unroll
    for (int p = 0; p < 8; ++p) ch.a[p] = ql[p] ? (u16)(ql[p] ^ sflip) : (u16)0;      wr(Kaug, 12);
    #pragma unroll
    for (int p = 0; p < 8; ++p) ch.a[p] = ql[8+p] ? (u16)(ql[8+p] ^ sflip) : (u16)0;  wr(Kaug, 13);
    #pragma unroll
    for (int p = 0; p < 8; ++p) ch.a[p] = 0;
    ch.a[0] = chi; ch.a[1] = clo;                     wr(Kaug, 14);
    ch.a[0] = 0; ch.a[1] = 0;                         wr(Kaug, 15);
    return;
  }

  const short* wf = (z == 0) ? wqf : (z == 1) ? wkf : wvf;
  const float* bias = (z == 0) ? bq : (z == 1) ? bk : bv;
  const int t = threadIdx.x, lane = t & 63, w = t >> 6;
  const int col = lane & 15, quad = lane >> 4;
  const int t0 = blockIdx.x * 64, head = blockIdx.y, c0 = head * 64;
  const int b = (t0 >= NT) ? 1 : 0;
  const int arow = t0 + w * 16 + col;
  f32x4 acc[4];
  #pragma unroll
  for (int ct = 0; ct < 4; ++ct) acc[ct] = (f32x4){0.f, 0.f, 0.f, 0.f};
  #pragma unroll
  for (int c = 0; c < 8; ++c) {
    short8 af = *(const short8*)&xfb[((size_t)(c * 4 + quad) * NTOK + arow) * 8];
    #pragma unroll
    for (int ct = 0; ct < 4; ++ct) {
      short8 bfr = *(const short8*)&wf[((size_t)(c * 4 + quad) * 256 + c0 + ct * 16 + col) * 8];
      acc[ct] = __builtin_amdgcn_mfma_f32_16x16x32_bf16(af, bfr, acc[ct], 0, 0, 0);
    }
  }
  const int r0 = t0 + w * 16 + quad * 4;
  const int n0l = r0 - b * NT;
  const int bh = b * NHD + head;
  if (z < 2) {
    short* dst = (z == 0) ? Qaug : Kaug;
    const float sc = (z == 0) ? 0.125f * LOG2E : 1.f;   // softmax scale + log2e in Q
    #pragma unroll
    for (int ct = 0; ct < 4; ++ct) {
      int chh = ct * 16 + col;
      float bb = bias[c0 + chh];
      int kq = chh >> 3, sub = chh & 7;
      #pragma unroll
      for (int reg = 0; reg < 4; ++reg) {
        float v = (acc[ct][reg] + bb) * sc;
        dst[((size_t)(bh * 16 + kq) * NT + n0l + reg) * 8 + sub] = (short)f2bf(v);
      }
    }
  } else {
    #pragma unroll
    for (int ct = 0; ct < 4; ++ct) {
      int d = ct * 16 + col;
      float bb = bias[c0 + d];
      #pragma unroll
      for (int reg = 0; reg < 4; ++reg) {
        int n = n0l + reg;
        // row-permuted V3 so P's natural Sᵀ register order is the A-operand order
        int chunk = (n >> 6) * 8 + ((n >> 5) & 1) * 4 + ((n >> 4) & 1) * 2 + ((n >> 2) & 1);
        int jj = (n & 3) + 4 * ((n >> 3) & 1);
        V3[((size_t)(bh * 288 + chunk) * 64 + d) * 8 + jj] = (short)f2bf(acc[ct][reg] + bb);
      }
    }
  }
}

// ================= K4: attention, PARTS=1, 8 waves, in-block kh merge ======
// grid (36 qt, 8 bh), 512 thr: wave w -> qh = w>>2 (32 q-rows), kh = w&3.
// Wave: 18 iters over its K rows (kh*32 + it*128), reg-dbuf prefetch,
// Sᵀ via 2 MFMA chains, p=exp2, PV with pre-permuted V. 4-way kh merge in LDS,
// normalize, store bf16 A/B-fragments for oproj. No opart/merge kernel.
__global__ __launch_bounds__(512) void attn_v4(
    const short* __restrict__ Qaug, const short* __restrict__ Kaug,
    const short* __restrict__ V3, short* __restrict__ afrag) {
  __shared__ float obuf[2][2][2][16][64];   // [qh][slot][nt][r][lane] 32 KB
  __shared__ float lbuf[2][2][32];
  __shared__ float lfin[2][32];

  const int t = threadIdx.x, lane = t & 63, w = t >> 6;
  const int qh = w >> 2, kh = w & 3;
  const int c32 = lane & 31, H = lane >> 5;
  const int qt = blockIdx.x, bh = blockIdx.y;
  const int q0 = qt * 64;
  const int qrow = q0 + qh * 32 + c32;
  const int bg = bh >> 2, hh = bh & 3;

  const short* qbase = Qaug + (size_t)bh * 16 * NT * 8;
  const short* kbase = Kaug + (size_t)bh * 16 * NT * 8;
  const short* vbase = V3 + (size_t)bh * 288 * 64 * 8;

  short8 qf[8];
  #pragma unroll
  for (int s = 0; s < 8; ++s)
    qf[s] = *(const short8*)&qbase[((size_t)(2 * s + H) * NT + qrow) * 8];

  f32x16 o[2];
  #pragma unroll
  for (int nt = 0; nt < 2; ++nt)
    #pragma unroll
    for (int r = 0; r < 16; ++r) o[nt][r] = 0.f;
  float lsum = 0.f;

  short8 kf[2][8], vf[2][4];
  {
    int j = kh * 32 + c32;
    #pragma unroll
    for (int s = 0; s < 8; ++s)
      kf[0][s] = *(const short8*)&kbase[((size_t)(2 * s + H) * NT + j) * 8];
    int cb = (kh >> 1) * 8 + (kh & 1) * 4;
    #pragma unroll
    for (int st = 0; st < 2; ++st)
      #pragma unroll
      for (int nt = 0; nt < 2; ++nt)
        vf[0][st * 2 + nt] = *(const short8*)&vbase[
            ((size_t)(cb + st * 2 + H) * 64 + nt * 32 + c32) * 8];
  }

  #pragma unroll
  for (int it = 0; it < 18; ++it) {
    const int cur = it & 1, nxt = cur ^ 1;
    if (it < 17) {   // prefetch next tile at top of iteration
      int jn = (it + 1) * 128 + kh * 32 + c32;
      #pragma unroll
      for (int s = 0; s < 8; ++s)
        kf[nxt][s] = *(const short8*)&kbase[((size_t)(2 * s + H) * NT + jn) * 8];
      int cb = ((it + 1) * 2 + (kh >> 1)) * 8 + (kh & 1) * 4;
      #pragma unroll
      for (int st = 0; st < 2; ++st)
        #pragma unroll
        for (int nt = 0; nt < 2; ++nt)
          vf[nxt][st * 2 + nt] = *(const short8*)&vbase[
              ((size_t)(cb + st * 2 + H) * 64 + nt * 32 + c32) * 8];
    }

    f32x16 s0, s1;
    #pragma unroll
    for (int r = 0; r < 16; ++r) { s0[r] = 0.f; s1[r] = 0.f; }
    #pragma unroll
    for (int s = 0; s < 4; ++s)
      s0 = __builtin_amdgcn_mfma_f32_32x32x16_bf16(kf[cur][s], qf[s], s0, 0, 0, 0);
    #pragma unroll
    for (int s = 4; s < 8; ++s)
      s1 = __builtin_amdgcn_mfma_f32_32x32x16_bf16(kf[cur][s], qf[s], s1, 0, 0, 0);

    float p[16];
    #pragma unroll
    for (int r = 0; r < 16; ++r) { p[r] = exp2f(s0[r] + s1[r]); lsum += p[r]; }

    short8 pf[2];
    #pragma unroll
    for (int st = 0; st < 2; ++st) {
      union { unsigned u[4]; short8 v; } pk;
      #pragma unroll
      for (int j2 = 0; j2 < 4; ++j2) {
        __hip_bfloat162 hh2 = __float22bfloat162_rn(
            make_float2(p[8 * st + 2 * j2], p[8 * st + 2 * j2 + 1]));
        pk.u[j2] = *(unsigned*)&hh2;
      }
      pf[st] = pk.v;
    }

    #pragma unroll
    for (int st = 0; st < 2; ++st)
      #pragma unroll
      for (int nt = 0; nt < 2; ++nt)
        o[nt] = __builtin_amdgcn_mfma_f32_32x32x16_bf16(pf[st], vf[cur][st * 2 + nt],
                                                        o[nt], 0, 0, 0);
  }

  lsum += __shfl_xor(lsum, 32, 64);

  // ---- 4-way kh merge in LDS
  if (kh >= 2) {
    #pragma unroll
    for (int nt = 0; nt < 2; ++nt)
      #pragma unroll
      for (int r = 0; r < 16; ++r) obuf[qh][kh - 2][nt][r][lane] = o[nt][r];
    if (H == 0) lbuf[qh][kh - 2][c32] = lsum;
  }
  __syncthreads();
  if (kh < 2) {
    #pragma unroll
    for (int nt = 0; nt < 2; ++nt)
      #pragma unroll
      for (int r = 0; r < 16; ++r) o[nt][r] += obuf[qh][kh][nt][r][lane];
    lsum += lbuf[qh][kh][c32];
  }
  __syncthreads();
  if (kh == 1) {
    #pragma unroll
    for (int nt = 0; nt < 2; ++nt)
      #pragma unroll
      for (int r = 0; r < 16; ++r) obuf[qh][1][nt][r][lane] = o[nt][r];
    if (H == 0) lbuf[qh][1][c32] = lsum;
  }
  __syncthreads();
  if (kh == 0) {
    #pragma unroll
    for (int nt = 0; nt < 2; ++nt)
      #pragma unroll
      for (int r = 0; r < 16; ++r) o[nt][r] += obuf[qh][1][nt][r][lane];
    lsum += lbuf[qh][1][c32];
    if (H == 0) lfin[qh][c32] = lsum;
  }
  __syncthreads();
  if (kh == 0) {
    float4 linv[4];
    #pragma unroll
    for (int g = 0; g < 4; ++g) {
      float4 lv = *(const float4*)&lfin[qh][8 * g + 4 * H];
      linv[g] = make_float4(1.f / lv.x, 1.f / lv.y, 1.f / lv.z, 1.f / lv.w);
    }
    #pragma unroll
    for (int nt = 0; nt < 2; ++nt) {
      int c = hh * 64 + nt * 32 + c32;
      size_t cbase = (size_t)(c >> 3) * NTOK * 8 + (c & 7);
      #pragma unroll
      for (int r = 0; r < 16; ++r) {
        float inv = (r & 3) == 0 ? linv[r >> 2].x : (r & 3) == 1 ? linv[r >> 2].y
                  : (r & 3) == 2 ? linv[r >> 2].z : linv[r >> 2].w;
        int n = q0 + qh * 32 + (r & 3) + 8 * (r >> 2) + 4 * H;
        afrag[cbase + (size_t)(bg * NT + n) * 8] = (short)f2bf(o[nt][r] * inv);
      }
    }
  }
}

// ================= K5: out projection, channel-split (72 x 4) ==============
__global__ __launch_bounds__(256) void oproj4(
    const short* __restrict__ afrag, const short* __restrict__ wof,
    const float* __restrict__ bo, void* __restrict__ outp,
    const int* __restrict__ flagp) {
  const int fp32 = *flagp;
  const int t = threadIdx.x, lane = t & 63, w = t >> 6;
  const int c32 = lane & 31, H = lane >> 5;
  const int t0 = blockIdx.x * 64, cg = blockIdx.y;
  const int b = (t0 >= NT) ? 1 : 0;
  const int nb0 = t0 - b * NT;
  const int tt = w & 1, chh = w >> 1;
  const int ch0 = cg * 64 + chh * 32;

  f32x16 acc;
  #pragma unroll
  for (int r = 0; r < 16; ++r) acc[r] = 0.f;
  #pragma unroll
  for (int s = 0; s < 16; ++s) {
    short8 a = *(const short8*)&wof[((size_t)(2 * s + H) * 256 + ch0 + c32) * 8];
    short8 bb = *(const short8*)&afrag[((size_t)(2 * s + H) * NTOK + t0 + tt * 32 + c32) * 8];
    acc = __builtin_amdgcn_mfma_f32_32x32x16_bf16(a, bb, acc, 0, 0, 0);
  }
  #pragma unroll
  for (int r = 0; r < 16; ++r) {
    int co = ch0 + (r & 3) + 8 * (r >> 2) + 4 * H;
    float v = acc[r] + bo[co];
    size_t off = ((size_t)(b * CC + co)) * NT + nb0 + tt * 32 + c32;
    if (fp32) ((float*)outp)[off] = v;
    else      ((u16*)outp)[off] = f2bf(v);
  }
}

extern "C" void kernel_launch(void* const* d_in, const int* in_sizes, int n_in,
                              void* d_out, int out_size, void* d_ws, size_t ws_size,
                              hipStream_t stream) {
  float* ws = (float*)d_ws;
  short* ws16 = (short*)d_ws;
  int* flag = (int*)d_ws;

  float* cb2 = ws + OFF_CB2;
  float* cbq = ws + OFF_CBQ; float* cbk = ws + OFF_CBK; float* cbv = ws + OFF_CBV;
  float* cbo = ws + OFF_CBO; float* cla = ws + OFF_CLA; float* cbeta = ws + OFF_CBETA;
  float* phif = ws + OFF_PHIF; float* phisq = ws + OFF_PHISQ;
  short* wqf = ws16 + OFF_WQF * 2;
  short* wkf = ws16 + OFF_WKF * 2;
  short* wvf = ws16 + OFF_WVF * 2;
  short* wof = ws16 + OFF_WOF * 2;
  short* w2f = ws16 + OFF_W2F * 2;
  short* xfb = ws16 + OFF_XFB * 2;
  short* qaug = ws16 + OFF_QAUG * 2;
  short* kaug = ws16 + OFF_KAUG * 2;
  short* v3   = ws16 + OFF_V3 * 2;
  short* afrag = ws16 + OFF_AFRAG * 2;

  setup_kernel<<<1158, 256, 0, stream>>>(
      d_in[0], d_in[3], d_in[5], d_in[7], d_in[9], d_in[13],
      d_in[14], d_in[4], d_in[6], d_in[8], d_in[10], d_in[15], d_in[16],
      ws, ws16, flag);
  prep_xf<<<dim3(72, 4), 256, 0, stream>>>(
      d_in[0], d_in[1], d_in[11], d_in[12], flag, w2f, cb2, phif, phisq, xfb);
  qkv_aug<<<dim3(72, 4, 4), 256, 0, stream>>>(xfb, wqf, wkf, wvf, cbq, cbk, cbv,
                                              phif, phisq, cla, cbeta,
                                              qaug, kaug, v3);
  attn_v4<<<dim3(36, 8), 512, 0, stream>>>(qaug, kaug, v3, afrag);
  oproj4<<<dim3(72, 4), 256, 0, stream>>>(afrag, wof, cbo, d_out, flag);
}

// Round 7
// 152.636 us; speedup vs baseline: 1.1632x; 1.0337x over previous
//
#include <hip/hip_runtime.h>
#include <hip/hip_bf16.h>
#include <math.h>

// Problem constants
#define BB   2
#define CC   256
#define NT   2304      // H*W
#define NTOK 4608      // B*NT
#define MM   16
#define NHD  4
#define HD   64
#define NBH  8
#define LOG2E 1.4426950408889634f

typedef unsigned short u16;
typedef __attribute__((ext_vector_type(8))) short short8;
typedef __attribute__((ext_vector_type(4))) float f32x4;
typedef __attribute__((ext_vector_type(16))) float f32x16;

__device__ __forceinline__ float bf2f(u16 u) {
  return __uint_as_float(((unsigned)u) << 16);
}
__device__ __forceinline__ u16 f2bf(float f) {
  unsigned u = __float_as_uint(f);
  unsigned r = 0x7FFFu + ((u >> 16) & 1u);
  return (u16)((u + r) >> 16);
}
__device__ __forceinline__ float ld_any(const void* p, size_t i, int fp32) {
  return fp32 ? ((const float*)p)[i] : bf2f(((const u16*)p)[i]);
}

// per-block dtype detect (bf16 pairs read as u32: low 16 bits look like bf16)
__device__ __forceinline__ int detect_fp32_block(const unsigned* __restrict__ x) {
  __shared__ int cnt4[4];
  __shared__ int resf;
  int t = threadIdx.x;
  unsigned u = x[t & 255];
  unsigned lo = u & 0xFFFFu;
  unsigned e = (lo >> 7) & 0xFFu;
  bool plausible = (lo == 0u) || (e >= 0x60u && e <= 0x88u);
  unsigned long long m = __ballot(plausible);
  if ((t & 63) == 0 && (t >> 6) < 4) cnt4[t >> 6] = __popcll(m);
  __syncthreads();
  if (t == 0) resf = ((cnt4[0] + cnt4[1] + cnt4[2] + cnt4[3]) < 128) ? 1 : 0;
  __syncthreads();
  return resf;
}

// ---------------- workspace layout (float offsets); flag = int at ws[0] ----
static constexpr size_t OFF_CB2   = 16;
static constexpr size_t OFF_CBQ   = OFF_CB2 + 256;
static constexpr size_t OFF_CBK   = OFF_CBQ + 256;
static constexpr size_t OFF_CBV   = OFF_CBK + 256;
static constexpr size_t OFF_CBO   = OFF_CBV + 256;
static constexpr size_t OFF_CLA   = OFF_CBO + 256;
static constexpr size_t OFF_CBETA = OFF_CLA + 16;
static constexpr size_t OFF_WQF   = 1344;                 // bf16 [32][256][8]
static constexpr size_t OFF_WKF   = OFF_WQF + 32768;
static constexpr size_t OFF_WVF   = OFF_WKF + 32768;
static constexpr size_t OFF_WOF   = OFF_WVF + 32768;
static constexpr size_t OFF_W2F   = OFF_WOF + 32768;      // bf16 [16][256][8]
static constexpr size_t OFF_XFB   = OFF_W2F + 16384;      // bf16 [32][4608][8]
static constexpr size_t OFF_QAUG  = OFF_XFB + 589824;     // bf16 [8][16][2304][8]
static constexpr size_t OFF_KAUG  = OFF_QAUG + 1179648;
static constexpr size_t OFF_V3    = OFF_KAUG + 1179648;   // bf16 [8][288][64][8] (row-permuted)
static constexpr size_t OFF_PHIF  = OFF_V3 + 589824;      // f32 [4608][16]
static constexpr size_t OFF_PHISQ = OFF_PHIF + 73728;     // f32 [4608]
static constexpr size_t OFF_AFRAG = OFF_PHISQ + 4608;     // bf16 [32][4608][8]
// end ~ 4.36M floats ~ 17.4 MiB

// ================= K1: pack weights + convert smalls + flag ================
__global__ __launch_bounds__(256) void setup_kernel(
    const void* __restrict__ x_raw,
    const void* __restrict__ Wq_r, const void* __restrict__ Wk_r,
    const void* __restrict__ Wv_r, const void* __restrict__ Wo_r,
    const void* __restrict__ W2_r,
    const void* __restrict__ b2_r, const void* __restrict__ bq_r,
    const void* __restrict__ bk_r, const void* __restrict__ bv_r,
    const void* __restrict__ bo_r, const void* __restrict__ la_r,
    const void* __restrict__ beta_r,
    float* __restrict__ ws, short* __restrict__ ws16, int* __restrict__ flagp) {
  const int fp32 = detect_fp32_block((const unsigned*)x_raw);
  const int bid = blockIdx.x, t = threadIdx.x;
  if (bid == 0 && t == 0) *flagp = fp32;
  if (bid < 1152) {
    // pack weights to bf16 fragment layout: W[n][k] -> [k>>3][n][k&7]
    int idx = bid * 256 + t;   // < 294912
    const void* srcs[5] = {Wq_r, Wk_r, Wv_r, Wo_r, W2_r};
    const int elems[5] = {65536, 65536, 65536, 65536, 32768};
    const int ksh[5] = {8, 8, 8, 8, 7};
    const size_t dsts[5] = {OFF_WQF * 2, OFF_WKF * 2, OFF_WVF * 2, OFF_WOF * 2, OFF_W2F * 2};
    int m = 0, off = idx;
    while (off >= elems[m]) { off -= elems[m]; ++m; }
    int ks = ksh[m];
    int n = off >> ks, k = off & ((1 << ks) - 1);
    float v = ld_any(srcs[m], off, fp32);
    ws16[dsts[m] + ((size_t)(k >> 3) * 256 + n) * 8 + (k & 7)] = (short)f2bf(v);
  } else {
    int idx = (bid - 1152) * 256 + t;   // < 1285
    const void* srcs[7] = {b2_r, bq_r, bk_r, bv_r, bo_r, la_r, beta_r};
    const int sizes[7] = {256, 256, 256, 256, 256, 1, 4};
    const int dsts[7] = {(int)OFF_CB2, (int)OFF_CBQ, (int)OFF_CBK, (int)OFF_CBV,
                         (int)OFF_CBO, (int)OFF_CLA, (int)OFF_CBETA};
    if (idx < 1285) {
      int seg = 0, off = idx;
      while (off >= sizes[seg]) { off -= sizes[seg]; ++seg; }
      ws[(size_t)dsts[seg] + off] = ld_any(srcs[seg], off, fp32);
    }
  }
}

// ================= K2: MLP + xf GEMM, channel-split (72 tiles x 4 chgroups) =
__global__ __launch_bounds__(256) void prep_xf(
    const void* __restrict__ x_raw, const void* __restrict__ phi_raw,
    const void* __restrict__ W1_r, const void* __restrict__ b1_r,
    const int* __restrict__ flagp,
    const short* __restrict__ w2f, const float* __restrict__ b2,
    float* __restrict__ phif, float* __restrict__ phisq,
    short* __restrict__ xfb) {
  __shared__ float phis[16][66];
  __shared__ float phisq_s[64];
  __shared__ float w1s[2048];
  __shared__ float b1s[128];
  __shared__ short hid[16][66][8];   // A-frags K=128: [kc][tok][8]

  const int fp32 = *flagp;
  const int t = threadIdx.x;
  const int n0 = blockIdx.x * 64, cg = blockIdx.y;
  const int b = (n0 >= NT) ? 1 : 0;
  const int nb0 = n0 - b * NT;

  #pragma unroll
  for (int i = 0; i < 4; ++i) {
    int idx = i * 256 + t;
    int m = idx >> 6, j = idx & 63;
    phis[m][j] = ld_any(phi_raw, ((size_t)(b * 16 + m)) * NT + nb0 + j, fp32);
  }
  #pragma unroll
  for (int i = 0; i < 8; ++i) w1s[i * 256 + t] = ld_any(W1_r, i * 256 + t, fp32);
  if (t < 128) b1s[t] = ld_any(b1_r, t, fp32);
  __syncthreads();

  if (t < 64) {
    float s = 0.f;
    #pragma unroll
    for (int m = 0; m < 16; ++m) { float p = phis[m][t]; s += p * p; }
    phisq_s[t] = s;
    if (cg == 0) phisq[n0 + t] = s;
  }
  if (cg == 0) {
    #pragma unroll
    for (int i = 0; i < 4; ++i) {
      int idx = i * 256 + t;
      int j = idx >> 4, m = idx & 15;
      phif[(size_t)(n0 + j) * 16 + m] = phis[m][j];
    }
  }
  {
    const int tok = t & 63, qtr = t >> 6;
    float pr[16];
    #pragma unroll
    for (int m = 0; m < 16; ++m) pr[m] = phis[m][tok];
    #pragma unroll
    for (int cc = 0; cc < 4; ++cc) {
      union { u16 a[8]; short8 v; } pk;
      #pragma unroll
      for (int s8 = 0; s8 < 8; ++s8) {
        int c = qtr * 32 + cc * 8 + s8;
        float acc = b1s[c];
        #pragma unroll
        for (int m = 0; m < 16; ++m) acc += pr[m] * w1s[c * 16 + m];
        float g = 0.5f * acc * (1.f + erff(acc * 0.70710678118654752f));
        pk.a[s8] = f2bf(g);
      }
      *(short8*)&hid[qtr * 4 + cc][tok][0] = pk.v;
    }
  }
  __syncthreads();

  // xf = hid @ W2^T + b2 + x^T for this block's 64 channels
  const int lane = t & 63, w = t >> 6;
  const int c32 = lane & 31, H = lane >> 5;
  const int tt = w & 1, chh = w >> 1;
  const int ch0 = cg * 64 + chh * 32;
  f32x16 acc;
  #pragma unroll
  for (int r = 0; r < 16; ++r) acc[r] = 0.f;
  #pragma unroll
  for (int s = 0; s < 8; ++s) {
    short8 a = *(const short8*)&hid[2 * s + H][tt * 32 + c32][0];
    short8 bb = *(const short8*)&w2f[((size_t)(2 * s + H) * 256 + ch0 + c32) * 8];
    acc = __builtin_amdgcn_mfma_f32_32x32x16_bf16(a, bb, acc, 0, 0, 0);
  }
  const int ch = ch0 + c32;
  const float bias = b2[ch];
  #pragma unroll
  for (int g = 0; g < 4; ++g) {
    int tok0 = tt * 32 + 8 * g + 4 * H;
    size_t xoff = ((size_t)(b * CC + ch)) * NT + nb0 + tok0;
    float4 xv;
    if (fp32) {
      xv = *(const float4*)&((const float*)x_raw)[xoff];
    } else {
      ushort4 xu = *(const ushort4*)&((const u16*)x_raw)[xoff];
      xv = make_float4(bf2f(xu.x), bf2f(xu.y), bf2f(xu.z), bf2f(xu.w));
    }
    float vals[4] = {xv.x, xv.y, xv.z, xv.w};
    #pragma unroll
    for (int e = 0; e < 4; ++e) {
      float v = acc[4 * g + e] + bias + vals[e];
      int gtok = n0 + tok0 + e;
      xfb[((size_t)(ch >> 3) * NTOK + gtok) * 8 + (ch & 7)] = (short)f2bf(v);
    }
  }
}

// ================= K3: QKV projection (MFMA) + fused aug ===================
__global__ __launch_bounds__(256) void qkv_aug(
    const short* __restrict__ xfb,
    const short* __restrict__ wqf, const short* __restrict__ wkf,
    const short* __restrict__ wvf,
    const float* __restrict__ bq, const float* __restrict__ bk,
    const float* __restrict__ bv,
    const float* __restrict__ phif, const float* __restrict__ phisq,
    const float* __restrict__ la, const float* __restrict__ beta,
    short* __restrict__ Qaug, short* __restrict__ Kaug, short* __restrict__ V3) {
  const int z = blockIdx.z;
  if (z == 3) {
    // ---- aug: fill Qaug/Kaug chunks 8..15 (geodesic, log2e folded)
    if (blockIdx.y != 0) return;
    int idx = blockIdx.x * 256 + threadIdx.x;
    if (idx >= NBH * NT) return;
    int bh = idx / NT, n = idx - bh * NT;
    int b = bh >> 2, h = bh & 3;
    float coef = -__expf(la[0]) * beta[h] * 0.17677669529663687f * LOG2E;
    float s2c = -2.f * coef;
    u16 sflip = (s2c < 0.f) ? 0x8000u : 0u;
    float s = sqrtf(fabsf(s2c));
    u16 qh[16], ql[16];
    #pragma unroll
    for (int m = 0; m < MM; ++m) {
      float v = s * phif[(size_t)(b * NT + n) * MM + m];
      u16 hv = f2bf(v);
      qh[m] = hv;
      ql[m] = f2bf(v - bf2f(hv));
    }
    float cp = coef * phisq[b * NT + n];
    u16 chi = f2bf(cp);
    u16 clo = f2bf(cp - bf2f(chi));
    union { u16 a[8]; short8 v; } ch;
    auto wr = [&](short* dst, int kq) {
      *(short8*)&dst[((size_t)(bh * 16 + kq) * NT + n) * 8] = ch.v;
    };
    #pragma unroll
    for (int p = 0; p < 8; ++p) ch.a[p] = qh[p];      wr(Qaug, 8);
    #pragma unroll
    for (int p = 0; p < 8; ++p) ch.a[p] = qh[8 + p];  wr(Qaug, 9);
    #pragma unroll
    for (int p = 0; p < 8; ++p) ch.a[p] = ql[p];      wr(Qaug, 10);
    #pragma unroll
    for (int p = 0; p < 8; ++p) ch.a[p] = ql[8 + p];  wr(Qaug, 11);
    #pragma unroll
    for (int p = 0; p < 8; ++p) ch.a[p] = qh[p];      wr(Qaug, 12);
    #pragma unroll
    for (int p = 0; p < 8; ++p) ch.a[p] = qh[8 + p];  wr(Qaug, 13);
    #pragma unroll
    for (int p = 0; p < 8; ++p) ch.a[p] = 0;
    ch.a[0] = 0x3F80u; ch.a[1] = 0x3F80u;             wr(Qaug, 14);
    ch.a[0] = 0; ch.a[1] = 0;                         wr(Qaug, 15);
    #pragma unroll
    for (int p = 0; p < 8; ++p) ch.a[p] = qh[p] ? (u16)(qh[p] ^ sflip) : (u16)0;      wr(Kaug, 8);
    #pragma unroll
    for (int p = 0; p < 8; ++p) ch.a[p] = qh[8+p] ? (u16)(qh[8+p] ^ sflip) : (u16)0;  wr(Kaug, 9);
    #pragma unroll
    for (int p = 0; p < 8; ++p) ch.a[p] = qh[p] ? (u16)(qh[p] ^ sflip) : (u16)0;      wr(Kaug, 10);
    #pragma unroll
    for (int p = 0; p < 8; ++p) ch.a[p] = qh[8+p] ? (u16)(qh[8+p] ^ sflip) : (u16)0;  wr(Kaug, 11);
    #pragma unroll
    for (int p = 0; p < 8; ++p) ch.a[p] = ql[p] ? (u16)(ql[p] ^ sflip) : (u16)0;      wr(Kaug, 12);
    #pragma unroll
    for (int p = 0; p < 8; ++p) ch.a[p] = ql[8+p] ? (u16)(ql[8+p] ^ sflip) : (u16)0;  wr(Kaug, 13);
    #pragma unroll
    for (int p = 0; p < 8; ++p) ch.a[p] = 0;
    ch.a[0] = chi; ch.a[1] = clo;                     wr(Kaug, 14);
    ch.a[0] = 0; ch.a[1] = 0;                         wr(Kaug, 15);
    return;
  }

  const short* wf = (z == 0) ? wqf : (z == 1) ? wkf : wvf;
  const float* bias = (z == 0) ? bq : (z == 1) ? bk : bv;
  const int t = threadIdx.x, lane = t & 63, w = t >> 6;
  const int col = lane & 15, quad = lane >> 4;
  const int t0 = blockIdx.x * 64, head = blockIdx.y, c0 = head * 64;
  const int b = (t0 >= NT) ? 1 : 0;
  const int arow = t0 + w * 16 + col;
  f32x4 acc[4];
  #pragma unroll
  for (int ct = 0; ct < 4; ++ct) acc[ct] = (f32x4){0.f, 0.f, 0.f, 0.f};
  #pragma unroll
  for (int c = 0; c < 8; ++c) {
    short8 af = *(const short8*)&xfb[((size_t)(c * 4 + quad) * NTOK + arow) * 8];
    #pragma unroll
    for (int ct = 0; ct < 4; ++ct) {
      short8 bfr = *(const short8*)&wf[((size_t)(c * 4 + quad) * 256 + c0 + ct * 16 + col) * 8];
      acc[ct] = __builtin_amdgcn_mfma_f32_16x16x32_bf16(af, bfr, acc[ct], 0, 0, 0);
    }
  }
  const int r0 = t0 + w * 16 + quad * 4;
  const int n0l = r0 - b * NT;
  const int bh = b * NHD + head;
  if (z < 2) {
    short* dst = (z == 0) ? Qaug : Kaug;
    const float sc = (z == 0) ? 0.125f * LOG2E : 1.f;   // softmax scale + log2e in Q
    #pragma unroll
    for (int ct = 0; ct < 4; ++ct) {
      int chh = ct * 16 + col;
      float bb = bias[c0 + chh];
      int kq = chh >> 3, sub = chh & 7;
      #pragma unroll
      for (int reg = 0; reg < 4; ++reg) {
        float v = (acc[ct][reg] + bb) * sc;
        dst[((size_t)(bh * 16 + kq) * NT + n0l + reg) * 8 + sub] = (short)f2bf(v);
      }
    }
  } else {
    #pragma unroll
    for (int ct = 0; ct < 4; ++ct) {
      int d = ct * 16 + col;
      float bb = bias[c0 + d];
      #pragma unroll
      for (int reg = 0; reg < 4; ++reg) {
        int n = n0l + reg;
        // row-permuted V3 so P's natural Sᵀ register order is the A-operand order
        int chunk = (n >> 6) * 8 + ((n >> 5) & 1) * 4 + ((n >> 4) & 1) * 2 + ((n >> 2) & 1);
        int jj = (n & 3) + 4 * ((n >> 3) & 1);
        V3[((size_t)(bh * 288 + chunk) * 64 + d) * 8 + jj] = (short)f2bf(acc[ct][reg] + bb);
      }
    }
  }
}

// ================= K4: attention v5 =======================================
// 576 linear blocks, bh = bid&7 (XCD-pinned: per-bh K/V stays in one L2),
// qt = bid>>3 (72 tiles of 32 q-rows). 256 thr = 4 waves = kh 0..3.
// Rotating single-buffer K/V register prefetch (load-after-use, ~1-iter lead),
// single QK acc chain (16 AGPR), exp2, pre-permuted V -> P needs no exchange.
// kh1..3 dump O/lsum to LDS once; kh0 merges, normalizes, stores afrag.
__global__ __launch_bounds__(256) void attn_v5(
    const short* __restrict__ Qaug, const short* __restrict__ Kaug,
    const short* __restrict__ V3, short* __restrict__ afrag) {
  __shared__ float obuf[3][2][16][64];   // 24 KB
  __shared__ float lbuf[3][32];
  __shared__ float lfin[32];

  const int t = threadIdx.x, lane = t & 63, kh = t >> 6;
  const int c32 = lane & 31, H = lane >> 5;
  const int bid = blockIdx.x;
  const int bh = bid & 7, qt = bid >> 3;
  const int q0 = qt * 32;
  const int bg = bh >> 2, hh = bh & 3;

  const short* qbase = Qaug + (size_t)bh * 16 * NT * 8;
  const short* kbase = Kaug + (size_t)bh * 16 * NT * 8;
  const short* vbase = V3 + (size_t)bh * 288 * 64 * 8;

  short8 qf[8];
  #pragma unroll
  for (int s = 0; s < 8; ++s)
    qf[s] = *(const short8*)&qbase[((size_t)(2 * s + H) * NT + q0 + c32) * 8];

  f32x16 o[2];
  #pragma unroll
  for (int nt = 0; nt < 2; ++nt)
    #pragma unroll
    for (int r = 0; r < 16; ++r) o[nt][r] = 0.f;
  float lsum = 0.f;

  short8 kf[8], vf[4];
  {
    int j = kh * 32 + c32;
    #pragma unroll
    for (int s = 0; s < 8; ++s)
      kf[s] = *(const short8*)&kbase[((size_t)(2 * s + H) * NT + j) * 8];
    int cb = (kh >> 1) * 8 + (kh & 1) * 4;
    #pragma unroll
    for (int st = 0; st < 2; ++st)
      #pragma unroll
      for (int nt = 0; nt < 2; ++nt)
        vf[st * 2 + nt] = *(const short8*)&vbase[
            ((size_t)(cb + st * 2 + H) * 64 + nt * 32 + c32) * 8];
  }

  auto iter = [&](int it, bool pref) {
    // S^T quadrant: D[j][i], lane col = i; single acc chain.
    // Rotating prefetch: kf[s] reloaded for it+1 right after its MFMA (WAR
    // keeps order; ~1-iter lead covers L2 latency).
    const int jn = (it + 1) * 128 + kh * 32 + c32;
    f32x16 sa;
    #pragma unroll
    for (int r = 0; r < 16; ++r) sa[r] = 0.f;
    #pragma unroll
    for (int s = 0; s < 8; ++s) {
      sa = __builtin_amdgcn_mfma_f32_32x32x16_bf16(kf[s], qf[s], sa, 0, 0, 0);
      if (pref)
        kf[s] = *(const short8*)&kbase[((size_t)(2 * s + H) * NT + jn) * 8];
    }

    float p[16];
    #pragma unroll
    for (int r = 0; r < 16; ++r) { p[r] = exp2f(sa[r]); lsum += p[r]; }

    short8 pf[2];
    #pragma unroll
    for (int st = 0; st < 2; ++st) {
      union { unsigned u[4]; short8 v; } pk;
      #pragma unroll
      for (int j2 = 0; j2 < 4; ++j2) {
        __hip_bfloat162 hh2 = __float22bfloat162_rn(
            make_float2(p[8 * st + 2 * j2], p[8 * st + 2 * j2 + 1]));
        pk.u[j2] = *(unsigned*)&hh2;
      }
      pf[st] = pk.v;
    }

    const int cbn = ((it + 1) * 2 + (kh >> 1)) * 8 + (kh & 1) * 4;
    #pragma unroll
    for (int st = 0; st < 2; ++st)
      #pragma unroll
      for (int nt = 0; nt < 2; ++nt) {
        o[nt] = __builtin_amdgcn_mfma_f32_32x32x16_bf16(pf[st], vf[st * 2 + nt],
                                                        o[nt], 0, 0, 0);
        if (pref)
          vf[st * 2 + nt] = *(const short8*)&vbase[
              ((size_t)(cbn + st * 2 + H) * 64 + nt * 32 + c32) * 8];
      }
  };

  #pragma unroll 1
  for (int it = 0; it < 17; ++it) iter(it, true);
  iter(17, false);

  lsum += __shfl_xor(lsum, 32, 64);

  // ---- 4-way kh merge: kh1..3 dump, one barrier, kh0 finishes
  if (kh != 0) {
    #pragma unroll
    for (int nt = 0; nt < 2; ++nt)
      #pragma unroll
      for (int r = 0; r < 16; ++r) obuf[kh - 1][nt][r][lane] = o[nt][r];
    if (H == 0) lbuf[kh - 1][c32] = lsum;
  }
  __syncthreads();
  if (kh == 0) {
    #pragma unroll
    for (int sl = 0; sl < 3; ++sl) {
      #pragma unroll
      for (int nt = 0; nt < 2; ++nt)
        #pragma unroll
        for (int r = 0; r < 16; ++r) o[nt][r] += obuf[sl][nt][r][lane];
      lsum += lbuf[sl][c32];
    }
    if (H == 0) lfin[c32] = lsum;   // same-wave LDS round-trip (no barrier)
    float4 linv[4];
    #pragma unroll
    for (int g = 0; g < 4; ++g) {
      float4 lv = *(const float4*)&lfin[8 * g + 4 * H];
      linv[g] = make_float4(1.f / lv.x, 1.f / lv.y, 1.f / lv.z, 1.f / lv.w);
    }
    #pragma unroll
    for (int nt = 0; nt < 2; ++nt) {
      int c = hh * 64 + nt * 32 + c32;
      size_t cbase = (size_t)(c >> 3) * NTOK * 8 + (c & 7);
      #pragma unroll
      for (int r = 0; r < 16; ++r) {
        float inv = (r & 3) == 0 ? linv[r >> 2].x : (r & 3) == 1 ? linv[r >> 2].y
                  : (r & 3) == 2 ? linv[r >> 2].z : linv[r >> 2].w;
        int n = q0 + (r & 3) + 8 * (r >> 2) + 4 * H;
        afrag[cbase + (size_t)(bg * NT + n) * 8] = (short)f2bf(o[nt][r] * inv);
      }
    }
  }
}

// ================= K5: out projection, channel-split (72 x 4) ==============
__global__ __launch_bounds__(256) void oproj4(
    const short* __restrict__ afrag, const short* __restrict__ wof,
    const float* __restrict__ bo, void* __restrict__ outp,
    const int* __restrict__ flagp) {
  const int fp32 = *flagp;
  const int t = threadIdx.x, lane = t & 63, w = t >> 6;
  const int c32 = lane & 31, H = lane >> 5;
  const int t0 = blockIdx.x * 64, cg = blockIdx.y;
  const int b = (t0 >= NT) ? 1 : 0;
  const int nb0 = t0 - b * NT;
  const int tt = w & 1, chh = w >> 1;
  const int ch0 = cg * 64 + chh * 32;

  f32x16 acc;
  #pragma unroll
  for (int r = 0; r < 16; ++r) acc[r] = 0.f;
  #pragma unroll
  for (int s = 0; s < 16; ++s) {
    short8 a = *(const short8*)&wof[((size_t)(2 * s + H) * 256 + ch0 + c32) * 8];
    short8 bb = *(const short8*)&afrag[((size_t)(2 * s + H) * NTOK + t0 + tt * 32 + c32) * 8];
    acc = __builtin_amdgcn_mfma_f32_32x32x16_bf16(a, bb, acc, 0, 0, 0);
  }
  #pragma unroll
  for (int r = 0; r < 16; ++r) {
    int co = ch0 + (r & 3) + 8 * (r >> 2) + 4 * H;
    float v = acc[r] + bo[co];
    size_t off = ((size_t)(b * CC + co)) * NT + nb0 + tt * 32 + c32;
    if (fp32) ((float*)outp)[off] = v;
    else      ((u16*)outp)[off] = f2bf(v);
  }
}

extern "C" void kernel_launch(void* const* d_in, const int* in_sizes, int n_in,
                              void* d_out, int out_size, void* d_ws, size_t ws_size,
                              hipStream_t stream) {
  float* ws = (float*)d_ws;
  short* ws16 = (short*)d_ws;
  int* flag = (int*)d_ws;

  float* cb2 = ws + OFF_CB2;
  float* cbq = ws + OFF_CBQ; float* cbk = ws + OFF_CBK; float* cbv = ws + OFF_CBV;
  float* cbo = ws + OFF_CBO; float* cla = ws + OFF_CLA; float* cbeta = ws + OFF_CBETA;
  float* phif = ws + OFF_PHIF; float* phisq = ws + OFF_PHISQ;
  short* wqf = ws16 + OFF_WQF * 2;
  short* wkf = ws16 + OFF_WKF * 2;
  short* wvf = ws16 + OFF_WVF * 2;
  short* wof = ws16 + OFF_WOF * 2;
  short* w2f = ws16 + OFF_W2F * 2;
  short* xfb = ws16 + OFF_XFB * 2;
  short* qaug = ws16 + OFF_QAUG * 2;
  short* kaug = ws16 + OFF_KAUG * 2;
  short* v3   = ws16 + OFF_V3 * 2;
  short* afrag = ws16 + OFF_AFRAG * 2;

  setup_kernel<<<1158, 256, 0, stream>>>(
      d_in[0], d_in[3], d_in[5], d_in[7], d_in[9], d_in[13],
      d_in[14], d_in[4], d_in[6], d_in[8], d_in[10], d_in[15], d_in[16],
      ws, ws16, flag);
  prep_xf<<<dim3(72, 4), 256, 0, stream>>>(
      d_in[0], d_in[1], d_in[11], d_in[12], flag, w2f, cb2, phif, phisq, xfb);
  qkv_aug<<<dim3(72, 4, 4), 256, 0, stream>>>(xfb, wqf, wkf, wvf, cbq, cbk, cbv,
                                              phif, phisq, cla, cbeta,
                                              qaug, kaug, v3);
  attn_v5<<<576, 256, 0, stream>>>(qaug, kaug, v3, afrag);
  oproj4<<<dim3(72, 4), 256, 0, stream>>>(afrag, wof, cbo, d_out, flag);
}

// Round 8
// 144.137 us; speedup vs baseline: 1.2318x; 1.0590x over previous
//
#include <hip/hip_runtime.h>
#include <hip/hip_bf16.h>
#include <math.h>

// Problem constants
#define BB   2
#define CC   256
#define NT   2304      // H*W
#define NTOK 4608      // B*NT
#define MM   16
#define NHD  4
#define HD   64
#define NBH  8
#define LOG2E 1.4426950408889634f

typedef unsigned short u16;
typedef __attribute__((ext_vector_type(8))) short short8;
typedef __attribute__((ext_vector_type(4))) float f32x4;
typedef __attribute__((ext_vector_type(16))) float f32x16;

__device__ __forceinline__ float bf2f(u16 u) {
  return __uint_as_float(((unsigned)u) << 16);
}
__device__ __forceinline__ u16 f2bf(float f) {
  unsigned u = __float_as_uint(f);
  unsigned r = 0x7FFFu + ((u >> 16) & 1u);
  return (u16)((u + r) >> 16);
}
__device__ __forceinline__ float ld_any(const void* p, size_t i, int fp32) {
  return fp32 ? ((const float*)p)[i] : bf2f(((const u16*)p)[i]);
}

// per-block dtype detect (bf16 pairs read as u32: low 16 bits look like bf16)
__device__ __forceinline__ int detect_fp32_block(const unsigned* __restrict__ x) {
  __shared__ int cnt4[4];
  __shared__ int resf;
  int t = threadIdx.x;
  unsigned u = x[t & 255];
  unsigned lo = u & 0xFFFFu;
  unsigned e = (lo >> 7) & 0xFFu;
  bool plausible = (lo == 0u) || (e >= 0x60u && e <= 0x88u);
  unsigned long long m = __ballot(plausible);
  if ((t & 63) == 0 && (t >> 6) < 4) cnt4[t >> 6] = __popcll(m);
  __syncthreads();
  if (t == 0) resf = ((cnt4[0] + cnt4[1] + cnt4[2] + cnt4[3]) < 128) ? 1 : 0;
  __syncthreads();
  return resf;
}

// ---------------- workspace layout (float offsets); flag = int at ws[0] ----
static constexpr size_t OFF_CB2   = 16;
static constexpr size_t OFF_CBQ   = OFF_CB2 + 256;
static constexpr size_t OFF_CBK   = OFF_CBQ + 256;
static constexpr size_t OFF_CBV   = OFF_CBK + 256;
static constexpr size_t OFF_CBO   = OFF_CBV + 256;
static constexpr size_t OFF_CLA   = OFF_CBO + 256;
static constexpr size_t OFF_CBETA = OFF_CLA + 16;
static constexpr size_t OFF_WQF   = 1344;                 // bf16 [32][256][8]
static constexpr size_t OFF_WKF   = OFF_WQF + 32768;
static constexpr size_t OFF_WVF   = OFF_WKF + 32768;
static constexpr size_t OFF_WOF   = OFF_WVF + 32768;
static constexpr size_t OFF_W2F   = OFF_WOF + 32768;      // bf16 [16][256][8]
static constexpr size_t OFF_XFB   = OFF_W2F + 16384;      // bf16 [32][4608][8]
static constexpr size_t OFF_QAUG  = OFF_XFB + 589824;     // bf16 [8][16][2304][8]
static constexpr size_t OFF_KAUG  = OFF_QAUG + 1179648;
static constexpr size_t OFF_V3    = OFF_KAUG + 1179648;   // bf16 [8][288][64][8] (row-permuted)
static constexpr size_t OFF_PHIF  = OFF_V3 + 589824;      // f32 [4608][16]
static constexpr size_t OFF_PHISQ = OFF_PHIF + 73728;     // f32 [4608]
static constexpr size_t OFF_AFRAG = OFF_PHISQ + 4608;     // bf16 [32][4608][8]
// end ~ 4.36M floats ~ 17.4 MiB

// ================= K1: pack weights + convert smalls + flag ================
__global__ __launch_bounds__(256) void setup_kernel(
    const void* __restrict__ x_raw,
    const void* __restrict__ Wq_r, const void* __restrict__ Wk_r,
    const void* __restrict__ Wv_r, const void* __restrict__ Wo_r,
    const void* __restrict__ W2_r,
    const void* __restrict__ b2_r, const void* __restrict__ bq_r,
    const void* __restrict__ bk_r, const void* __restrict__ bv_r,
    const void* __restrict__ bo_r, const void* __restrict__ la_r,
    const void* __restrict__ beta_r,
    float* __restrict__ ws, short* __restrict__ ws16, int* __restrict__ flagp) {
  const int fp32 = detect_fp32_block((const unsigned*)x_raw);
  const int bid = blockIdx.x, t = threadIdx.x;
  if (bid == 0 && t == 0) *flagp = fp32;
  if (bid < 1152) {
    // pack weights to bf16 fragment layout: W[n][k] -> [k>>3][n][k&7]
    int idx = bid * 256 + t;   // < 294912
    const void* srcs[5] = {Wq_r, Wk_r, Wv_r, Wo_r, W2_r};
    const int elems[5] = {65536, 65536, 65536, 65536, 32768};
    const int ksh[5] = {8, 8, 8, 8, 7};
    const size_t dsts[5] = {OFF_WQF * 2, OFF_WKF * 2, OFF_WVF * 2, OFF_WOF * 2, OFF_W2F * 2};
    int m = 0, off = idx;
    while (off >= elems[m]) { off -= elems[m]; ++m; }
    int ks = ksh[m];
    int n = off >> ks, k = off & ((1 << ks) - 1);
    float v = ld_any(srcs[m], off, fp32);
    ws16[dsts[m] + ((size_t)(k >> 3) * 256 + n) * 8 + (k & 7)] = (short)f2bf(v);
  } else {
    int idx = (bid - 1152) * 256 + t;   // < 1285
    const void* srcs[7] = {b2_r, bq_r, bk_r, bv_r, bo_r, la_r, beta_r};
    const int sizes[7] = {256, 256, 256, 256, 256, 1, 4};
    const int dsts[7] = {(int)OFF_CB2, (int)OFF_CBQ, (int)OFF_CBK, (int)OFF_CBV,
                         (int)OFF_CBO, (int)OFF_CLA, (int)OFF_CBETA};
    if (idx < 1285) {
      int seg = 0, off = idx;
      while (off >= sizes[seg]) { off -= sizes[seg]; ++seg; }
      ws[(size_t)dsts[seg] + off] = ld_any(srcs[seg], off, fp32);
    }
  }
}

// ================= K2: MLP + xf GEMM, channel-split (72 tiles x 4 chgroups) =
__global__ __launch_bounds__(256) void prep_xf(
    const void* __restrict__ x_raw, const void* __restrict__ phi_raw,
    const void* __restrict__ W1_r, const void* __restrict__ b1_r,
    const int* __restrict__ flagp,
    const short* __restrict__ w2f, const float* __restrict__ b2,
    float* __restrict__ phif, float* __restrict__ phisq,
    short* __restrict__ xfb) {
  __shared__ float phis[16][66];
  __shared__ float phisq_s[64];
  __shared__ float w1s[2048];
  __shared__ float b1s[128];
  __shared__ short hid[16][66][8];   // A-frags K=128: [kc][tok][8]

  const int fp32 = *flagp;
  const int t = threadIdx.x;
  const int n0 = blockIdx.x * 64, cg = blockIdx.y;
  const int b = (n0 >= NT) ? 1 : 0;
  const int nb0 = n0 - b * NT;

  #pragma unroll
  for (int i = 0; i < 4; ++i) {
    int idx = i * 256 + t;
    int m = idx >> 6, j = idx & 63;
    phis[m][j] = ld_any(phi_raw, ((size_t)(b * 16 + m)) * NT + nb0 + j, fp32);
  }
  #pragma unroll
  for (int i = 0; i < 8; ++i) w1s[i * 256 + t] = ld_any(W1_r, i * 256 + t, fp32);
  if (t < 128) b1s[t] = ld_any(b1_r, t, fp32);
  __syncthreads();

  if (t < 64) {
    float s = 0.f;
    #pragma unroll
    for (int m = 0; m < 16; ++m) { float p = phis[m][t]; s += p * p; }
    phisq_s[t] = s;
    if (cg == 0) phisq[n0 + t] = s;
  }
  if (cg == 0) {
    #pragma unroll
    for (int i = 0; i < 4; ++i) {
      int idx = i * 256 + t;
      int j = idx >> 4, m = idx & 15;
      phif[(size_t)(n0 + j) * 16 + m] = phis[m][j];
    }
  }
  {
    const int tok = t & 63, qtr = t >> 6;
    float pr[16];
    #pragma unroll
    for (int m = 0; m < 16; ++m) pr[m] = phis[m][tok];
    #pragma unroll
    for (int cc = 0; cc < 4; ++cc) {
      union { u16 a[8]; short8 v; } pk;
      #pragma unroll
      for (int s8 = 0; s8 < 8; ++s8) {
        int c = qtr * 32 + cc * 8 + s8;
        float acc = b1s[c];
        #pragma unroll
        for (int m = 0; m < 16; ++m) acc += pr[m] * w1s[c * 16 + m];
        float g = 0.5f * acc * (1.f + erff(acc * 0.70710678118654752f));
        pk.a[s8] = f2bf(g);
      }
      *(short8*)&hid[qtr * 4 + cc][tok][0] = pk.v;
    }
  }
  __syncthreads();

  // xf = hid @ W2^T + b2 + x^T for this block's 64 channels
  const int lane = t & 63, w = t >> 6;
  const int c32 = lane & 31, H = lane >> 5;
  const int tt = w & 1, chh = w >> 1;
  const int ch0 = cg * 64 + chh * 32;
  f32x16 acc;
  #pragma unroll
  for (int r = 0; r < 16; ++r) acc[r] = 0.f;
  #pragma unroll
  for (int s = 0; s < 8; ++s) {
    short8 a = *(const short8*)&hid[2 * s + H][tt * 32 + c32][0];
    short8 bb = *(const short8*)&w2f[((size_t)(2 * s + H) * 256 + ch0 + c32) * 8];
    acc = __builtin_amdgcn_mfma_f32_32x32x16_bf16(a, bb, acc, 0, 0, 0);
  }
  const int ch = ch0 + c32;
  const float bias = b2[ch];
  #pragma unroll
  for (int g = 0; g < 4; ++g) {
    int tok0 = tt * 32 + 8 * g + 4 * H;
    size_t xoff = ((size_t)(b * CC + ch)) * NT + nb0 + tok0;
    float4 xv;
    if (fp32) {
      xv = *(const float4*)&((const float*)x_raw)[xoff];
    } else {
      ushort4 xu = *(const ushort4*)&((const u16*)x_raw)[xoff];
      xv = make_float4(bf2f(xu.x), bf2f(xu.y), bf2f(xu.z), bf2f(xu.w));
    }
    float vals[4] = {xv.x, xv.y, xv.z, xv.w};
    #pragma unroll
    for (int e = 0; e < 4; ++e) {
      float v = acc[4 * g + e] + bias + vals[e];
      int gtok = n0 + tok0 + e;
      xfb[((size_t)(ch >> 3) * NTOK + gtok) * 8 + (ch & 7)] = (short)f2bf(v);
    }
  }
}

// ================= K3: QKV projection (MFMA) + fused aug ===================
// aug writes only the chunks attn_v6 reads: Q 8,9 (qh), 10,11 (ql);
// K 8,9 (kh), 12,13 (kl), 14 (chi,clo). Q12-15, K10,11,15 unused now.
__global__ __launch_bounds__(256) void qkv_aug(
    const short* __restrict__ xfb,
    const short* __restrict__ wqf, const short* __restrict__ wkf,
    const short* __restrict__ wvf,
    const float* __restrict__ bq, const float* __restrict__ bk,
    const float* __restrict__ bv,
    const float* __restrict__ phif, const float* __restrict__ phisq,
    const float* __restrict__ la, const float* __restrict__ beta,
    short* __restrict__ Qaug, short* __restrict__ Kaug, short* __restrict__ V3) {
  const int z = blockIdx.z;
  if (z == 3) {
    if (blockIdx.y != 0) return;
    int idx = blockIdx.x * 256 + threadIdx.x;
    if (idx >= NBH * NT) return;
    int bh = idx / NT, n = idx - bh * NT;
    int b = bh >> 2, h = bh & 3;
    float coef = -__expf(la[0]) * beta[h] * 0.17677669529663687f * LOG2E;
    float s2c = -2.f * coef;
    u16 sflip = (s2c < 0.f) ? 0x8000u : 0u;
    float s = sqrtf(fabsf(s2c));
    u16 qh[16], ql[16];
    #pragma unroll
    for (int m = 0; m < MM; ++m) {
      float v = s * phif[(size_t)(b * NT + n) * MM + m];
      u16 hv = f2bf(v);
      qh[m] = hv;
      ql[m] = f2bf(v - bf2f(hv));
    }
    float cp = coef * phisq[b * NT + n];
    u16 chi = f2bf(cp);
    u16 clo = f2bf(cp - bf2f(chi));
    union { u16 a[8]; short8 v; } ch;
    auto wr = [&](short* dst, int kq) {
      *(short8*)&dst[((size_t)(bh * 16 + kq) * NT + n) * 8] = ch.v;
    };
    #pragma unroll
    for (int p = 0; p < 8; ++p) ch.a[p] = qh[p];      wr(Qaug, 8);
    #pragma unroll
    for (int p = 0; p < 8; ++p) ch.a[p] = qh[8 + p];  wr(Qaug, 9);
    #pragma unroll
    for (int p = 0; p < 8; ++p) ch.a[p] = ql[p];      wr(Qaug, 10);
    #pragma unroll
    for (int p = 0; p < 8; ++p) ch.a[p] = ql[8 + p];  wr(Qaug, 11);
    #pragma unroll
    for (int p = 0; p < 8; ++p) ch.a[p] = qh[p] ? (u16)(qh[p] ^ sflip) : (u16)0;      wr(Kaug, 8);
    #pragma unroll
    for (int p = 0; p < 8; ++p) ch.a[p] = qh[8+p] ? (u16)(qh[8+p] ^ sflip) : (u16)0;  wr(Kaug, 9);
    #pragma unroll
    for (int p = 0; p < 8; ++p) ch.a[p] = ql[p] ? (u16)(ql[p] ^ sflip) : (u16)0;      wr(Kaug, 12);
    #pragma unroll
    for (int p = 0; p < 8; ++p) ch.a[p] = ql[8+p] ? (u16)(ql[8+p] ^ sflip) : (u16)0;  wr(Kaug, 13);
    #pragma unroll
    for (int p = 0; p < 8; ++p) ch.a[p] = 0;
    ch.a[0] = chi; ch.a[1] = clo;                     wr(Kaug, 14);
    return;
  }

  const short* wf = (z == 0) ? wqf : (z == 1) ? wkf : wvf;
  const float* bias = (z == 0) ? bq : (z == 1) ? bk : bv;
  const int t = threadIdx.x, lane = t & 63, w = t >> 6;
  const int col = lane & 15, quad = lane >> 4;
  const int t0 = blockIdx.x * 64, head = blockIdx.y, c0 = head * 64;
  const int b = (t0 >= NT) ? 1 : 0;
  const int arow = t0 + w * 16 + col;
  f32x4 acc[4];
  #pragma unroll
  for (int ct = 0; ct < 4; ++ct) acc[ct] = (f32x4){0.f, 0.f, 0.f, 0.f};
  #pragma unroll
  for (int c = 0; c < 8; ++c) {
    short8 af = *(const short8*)&xfb[((size_t)(c * 4 + quad) * NTOK + arow) * 8];
    #pragma unroll
    for (int ct = 0; ct < 4; ++ct) {
      short8 bfr = *(const short8*)&wf[((size_t)(c * 4 + quad) * 256 + c0 + ct * 16 + col) * 8];
      acc[ct] = __builtin_amdgcn_mfma_f32_16x16x32_bf16(af, bfr, acc[ct], 0, 0, 0);
    }
  }
  const int r0 = t0 + w * 16 + quad * 4;
  const int n0l = r0 - b * NT;
  const int bh = b * NHD + head;
  if (z < 2) {
    short* dst = (z == 0) ? Qaug : Kaug;
    const float sc = (z == 0) ? 0.125f * LOG2E : 1.f;   // softmax scale + log2e in Q
    #pragma unroll
    for (int ct = 0; ct < 4; ++ct) {
      int chh = ct * 16 + col;
      float bb = bias[c0 + chh];
      int kq = chh >> 3, sub = chh & 7;
      #pragma unroll
      for (int reg = 0; reg < 4; ++reg) {
        float v = (acc[ct][reg] + bb) * sc;
        dst[((size_t)(bh * 16 + kq) * NT + n0l + reg) * 8 + sub] = (short)f2bf(v);
      }
    }
  } else {
    #pragma unroll
    for (int ct = 0; ct < 4; ++ct) {
      int d = ct * 16 + col;
      float bb = bias[c0 + d];
      #pragma unroll
      for (int reg = 0; reg < 4; ++reg) {
        int n = n0l + reg;
        // row-permuted V3 so P's natural Sᵀ register order is the A-operand order
        int chunk = (n >> 6) * 8 + ((n >> 5) & 1) * 4 + ((n >> 4) & 1) * 2 + ((n >> 2) & 1);
        int jj = (n & 3) + 4 * ((n >> 3) & 1);
        V3[((size_t)(bh * 288 + chunk) * 64 + d) * 8 + jj] = (short)f2bf(acc[ct][reg] + bb);
      }
    }
  }
}

// ================= K4: attention v6 =======================================
// 576 linear blocks, bh = bid&7 (XCD-pinned), qt = bid>>3 (72 x 32 q-rows).
// 256 thr = 4 waves = kh 0..3, 18 iters of 128 K-rows each.
// Register-deduped augmented dims (each MFMA is self-contained, so duplicate
// chunks reuse one register): 8 MFMAs over 7 kf + 7 qf regs:
//   s0-3: qk; (kf4,qf4)=kh*qh; (kf4,qf5)=kh*ql; (kf6,qf4)=kl*qh;
//   (kf7,qf7): kf7 = chunk14 (chi,clo) all lanes; qf7 = (1,1,0..)|H0, 0|H1
//   -> H1 half contributes 0 regardless of kf7 content.
// __launch_bounds__(256,3) forces <=~168 regs -> 3 waves/SIMD -> 576 blocks
// fit one dispatch round (3 blocks/CU).
__global__ __launch_bounds__(256, 3) void attn_v6(
    const short* __restrict__ Qaug, const short* __restrict__ Kaug,
    const short* __restrict__ V3, short* __restrict__ afrag) {
  __shared__ float obuf[3][2][16][64];   // 24 KB
  __shared__ float lbuf[3][32];
  __shared__ float lfin[32];

  const int t = threadIdx.x, lane = t & 63, kh = t >> 6;
  const int c32 = lane & 31, H = lane >> 5;
  const int bid = blockIdx.x;
  const int bh = bid & 7, qt = bid >> 3;
  const int q0 = qt * 32;
  const int bg = bh >> 2, hh = bh & 3;

  const short* qbase = Qaug + (size_t)bh * 16 * NT * 8;
  const short* kbase = Kaug + (size_t)bh * 16 * NT * 8;
  const short* vbase = V3 + (size_t)bh * 288 * 64 * 8;

  // Q fragments: chunks 0..11 (s=0..5); qf7 = constant (1,1,0..)/0
  short8 qf[6];
  #pragma unroll
  for (int s = 0; s < 6; ++s)
    qf[s] = *(const short8*)&qbase[((size_t)(2 * s + H) * NT + q0 + c32) * 8];
  short8 qf7;
  {
    union { u16 a[8]; short8 v; } c7;
    #pragma unroll
    for (int p = 0; p < 8; ++p) c7.a[p] = 0;
    if (H == 0) { c7.a[0] = 0x3F80u; c7.a[1] = 0x3F80u; }
    qf7 = c7.v;
  }

  f32x16 o[2];
  #pragma unroll
  for (int nt = 0; nt < 2; ++nt)
    #pragma unroll
    for (int r = 0; r < 16; ++r) o[nt][r] = 0.f;
  float lsum = 0.f;

  short8 kf[5], kf6, kf7, vf[4];
  {
    int j = kh * 32 + c32;
    #pragma unroll
    for (int s = 0; s < 5; ++s)
      kf[s] = *(const short8*)&kbase[((size_t)(2 * s + H) * NT + j) * 8];
    kf6 = *(const short8*)&kbase[((size_t)(12 + H) * NT + j) * 8];
    kf7 = *(const short8*)&kbase[((size_t)14 * NT + j) * 8];
    int cb = (kh >> 1) * 8 + (kh & 1) * 4;
    #pragma unroll
    for (int st = 0; st < 2; ++st)
      #pragma unroll
      for (int nt = 0; nt < 2; ++nt)
        vf[st * 2 + nt] = *(const short8*)&vbase[
            ((size_t)(cb + st * 2 + H) * 64 + nt * 32 + c32) * 8];
  }

  auto iter = [&](int it, bool pref) {
    const int jn = (it + 1) * 128 + kh * 32 + c32;
    f32x16 sa;
    #pragma unroll
    for (int r = 0; r < 16; ++r) sa[r] = 0.f;
    #pragma unroll
    for (int s = 0; s < 4; ++s) {
      sa = __builtin_amdgcn_mfma_f32_32x32x16_bf16(kf[s], qf[s], sa, 0, 0, 0);
      if (pref)
        kf[s] = *(const short8*)&kbase[((size_t)(2 * s + H) * NT + jn) * 8];
    }
    sa = __builtin_amdgcn_mfma_f32_32x32x16_bf16(kf[4], qf[4], sa, 0, 0, 0);  // kh*qh
    sa = __builtin_amdgcn_mfma_f32_32x32x16_bf16(kf[4], qf[5], sa, 0, 0, 0);  // kh*ql
    if (pref) kf[4] = *(const short8*)&kbase[((size_t)(8 + H) * NT + jn) * 8];
    sa = __builtin_amdgcn_mfma_f32_32x32x16_bf16(kf6, qf[4], sa, 0, 0, 0);    // kl*qh
    if (pref) kf6 = *(const short8*)&kbase[((size_t)(12 + H) * NT + jn) * 8];
    sa = __builtin_amdgcn_mfma_f32_32x32x16_bf16(kf7, qf7, sa, 0, 0, 0);      // psq_j
    if (pref) kf7 = *(const short8*)&kbase[((size_t)14 * NT + jn) * 8];

    float p[16];
    #pragma unroll
    for (int r = 0; r < 16; ++r) { p[r] = exp2f(sa[r]); lsum += p[r]; }

    short8 pf[2];
    #pragma unroll
    for (int st = 0; st < 2; ++st) {
      union { unsigned u[4]; short8 v; } pk;
      #pragma unroll
      for (int j2 = 0; j2 < 4; ++j2) {
        __hip_bfloat162 hh2 = __float22bfloat162_rn(
            make_float2(p[8 * st + 2 * j2], p[8 * st + 2 * j2 + 1]));
        pk.u[j2] = *(unsigned*)&hh2;
      }
      pf[st] = pk.v;
    }

    const int cbn = ((it + 1) * 2 + (kh >> 1)) * 8 + (kh & 1) * 4;
    #pragma unroll
    for (int st = 0; st < 2; ++st)
      #pragma unroll
      for (int nt = 0; nt < 2; ++nt) {
        o[nt] = __builtin_amdgcn_mfma_f32_32x32x16_bf16(pf[st], vf[st * 2 + nt],
                                                        o[nt], 0, 0, 0);
        if (pref)
          vf[st * 2 + nt] = *(const short8*)&vbase[
              ((size_t)(cbn + st * 2 + H) * 64 + nt * 32 + c32) * 8];
      }
  };

  #pragma unroll 1
  for (int it = 0; it < 17; ++it) iter(it, true);
  iter(17, false);

  lsum += __shfl_xor(lsum, 32, 64);

  // ---- 4-way kh merge: kh1..3 dump, one barrier, kh0 finishes
  if (kh != 0) {
    #pragma unroll
    for (int nt = 0; nt < 2; ++nt)
      #pragma unroll
      for (int r = 0; r < 16; ++r) obuf[kh - 1][nt][r][lane] = o[nt][r];
    if (H == 0) lbuf[kh - 1][c32] = lsum;
  }
  __syncthreads();
  if (kh == 0) {
    #pragma unroll
    for (int sl = 0; sl < 3; ++sl) {
      #pragma unroll
      for (int nt = 0; nt < 2; ++nt)
        #pragma unroll
        for (int r = 0; r < 16; ++r) o[nt][r] += obuf[sl][nt][r][lane];
      lsum += lbuf[sl][c32];
    }
    if (H == 0) lfin[c32] = lsum;   // same-wave LDS round-trip (no barrier)
    float4 linv[4];
    #pragma unroll
    for (int g = 0; g < 4; ++g) {
      float4 lv = *(const float4*)&lfin[8 * g + 4 * H];
      linv[g] = make_float4(1.f / lv.x, 1.f / lv.y, 1.f / lv.z, 1.f / lv.w);
    }
    #pragma unroll
    for (int nt = 0; nt < 2; ++nt) {
      int c = hh * 64 + nt * 32 + c32;
      size_t cbase = (size_t)(c >> 3) * NTOK * 8 + (c & 7);
      #pragma unroll
      for (int r = 0; r < 16; ++r) {
        float inv = (r & 3) == 0 ? linv[r >> 2].x : (r & 3) == 1 ? linv[r >> 2].y
                  : (r & 3) == 2 ? linv[r >> 2].z : linv[r >> 2].w;
        int n = q0 + (r & 3) + 8 * (r >> 2) + 4 * H;
        afrag[cbase + (size_t)(bg * NT + n) * 8] = (short)f2bf(o[nt][r] * inv);
      }
    }
  }
}

// ================= K5: out projection, channel-split (72 x 4) ==============
__global__ __launch_bounds__(256) void oproj4(
    const short* __restrict__ afrag, const short* __restrict__ wof,
    const float* __restrict__ bo, void* __restrict__ outp,
    const int* __restrict__ flagp) {
  const int fp32 = *flagp;
  const int t = threadIdx.x, lane = t & 63, w = t >> 6;
  const int c32 = lane & 31, H = lane >> 5;
  const int t0 = blockIdx.x * 64, cg = blockIdx.y;
  const int b = (t0 >= NT) ? 1 : 0;
  const int nb0 = t0 - b * NT;
  const int tt = w & 1, chh = w >> 1;
  const int ch0 = cg * 64 + chh * 32;

  f32x16 acc;
  #pragma unroll
  for (int r = 0; r < 16; ++r) acc[r] = 0.f;
  #pragma unroll
  for (int s = 0; s < 16; ++s) {
    short8 a = *(const short8*)&wof[((size_t)(2 * s + H) * 256 + ch0 + c32) * 8];
    short8 bb = *(const short8*)&afrag[((size_t)(2 * s + H) * NTOK + t0 + tt * 32 + c32) * 8];
    acc = __builtin_amdgcn_mfma_f32_32x32x16_bf16(a, bb, acc, 0, 0, 0);
  }
  #pragma unroll
  for (int r = 0; r < 16; ++r) {
    int co = ch0 + (r & 3) + 8 * (r >> 2) + 4 * H;
    float v = acc[r] + bo[co];
    size_t off = ((size_t)(b * CC + co)) * NT + nb0 + tt * 32 + c32;
    if (fp32) ((float*)outp)[off] = v;
    else      ((u16*)outp)[off] = f2bf(v);
  }
}

extern "C" void kernel_launch(void* const* d_in, const int* in_sizes, int n_in,
                              void* d_out, int out_size, void* d_ws, size_t ws_size,
                              hipStream_t stream) {
  float* ws = (float*)d_ws;
  short* ws16 = (short*)d_ws;
  int* flag = (int*)d_ws;

  float* cb2 = ws + OFF_CB2;
  float* cbq = ws + OFF_CBQ; float* cbk = ws + OFF_CBK; float* cbv = ws + OFF_CBV;
  float* cbo = ws + OFF_CBO; float* cla = ws + OFF_CLA; float* cbeta = ws + OFF_CBETA;
  float* phif = ws + OFF_PHIF; float* phisq = ws + OFF_PHISQ;
  short* wqf = ws16 + OFF_WQF * 2;
  short* wkf = ws16 + OFF_WKF * 2;
  short* wvf = ws16 + OFF_WVF * 2;
  short* wof = ws16 + OFF_WOF * 2;
  short* w2f = ws16 + OFF_W2F * 2;
  short* xfb = ws16 + OFF_XFB * 2;
  short* qaug = ws16 + OFF_QAUG * 2;
  short* kaug = ws16 + OFF_KAUG * 2;
  short* v3   = ws16 + OFF_V3 * 2;
  short* afrag = ws16 + OFF_AFRAG * 2;

  setup_kernel<<<1158, 256, 0, stream>>>(
      d_in[0], d_in[3], d_in[5], d_in[7], d_in[9], d_in[13],
      d_in[14], d_in[4], d_in[6], d_in[8], d_in[10], d_in[15], d_in[16],
      ws, ws16, flag);
  prep_xf<<<dim3(72, 4), 256, 0, stream>>>(
      d_in[0], d_in[1], d_in[11], d_in[12], flag, w2f, cb2, phif, phisq, xfb);
  qkv_aug<<<dim3(72, 4, 4), 256, 0, stream>>>(xfb, wqf, wkf, wvf, cbq, cbk, cbv,
                                              phif, phisq, cla, cbeta,
                                              qaug, kaug, v3);
  attn_v6<<<576, 256, 0, stream>>>(qaug, kaug, v3, afrag);
  oproj4<<<dim3(72, 4), 256, 0, stream>>>(afrag, wof, cbo, d_out, flag);
}